// Round 9
// baseline (1246.134 us; speedup 1.0000x reference)
//
#include <hip/hip_runtime.h>
#include <hip/hip_bf16.h>
#include <cstdint>
#include <cstddef>

#define NN 20000
#define NE 640000
#define NF 64
#define HD 256
#define NL 4
#define HTS 640   // hT row stride in shorts: 1280 B = 5x256 B (destaggers HBM channels)
#define SR 32     // node strip rows: 625 blocks (R8's SR=16 doubled weight traffic: reverted)
#define NB 79     // scan blocks: ceil(NN/256)

typedef __attribute__((ext_vector_type(8))) short short8;
typedef __attribute__((ext_vector_type(4))) float f32x4;
typedef __attribute__((ext_vector_type(2))) float f32x2;

__device__ __forceinline__ float bf2f(unsigned short u){
  union { unsigned int i; float f; } x; x.i = ((unsigned int)u) << 16; return x.f;
}
__device__ __forceinline__ unsigned short f2bf(float f){
  union { float f; unsigned int i; } x; x.f = f;
  unsigned int r = x.i + 0x7FFFu + ((x.i >> 16) & 1u);   // RNE
  return (unsigned short)(r >> 16);
}
// packed 2xf32 -> 2xbf16 (v_cvt_pk_bf16_f32 on gfx950, RNE)
__device__ __forceinline__ unsigned int pk2bf(float a, float b){
  union { __hip_bfloat162 h; unsigned int u; } cv;
  cv.h = __float22bfloat162_rn(float2{a, b});
  return cv.u;
}
// silu via guaranteed-native v_exp_f32 + v_rcp_f32
__device__ __forceinline__ float silu_f(float v){
  float e = __builtin_amdgcn_exp2f(v * -1.442695041f);
  return v * __builtin_amdgcn_rcpf(1.0f + e);
}
// packed silu on 2 lanes: pk mul/add around the 2 scalar trans ops
__device__ __forceinline__ f32x2 silu2(f32x2 v){
  f32x2 t = v * (f32x2){-1.442695041f, -1.442695041f};   // v_pk_mul_f32
  f32x2 e = (f32x2){__builtin_amdgcn_exp2f(t.x), __builtin_amdgcn_exp2f(t.y)};
  f32x2 d = e + (f32x2){1.0f, 1.0f};                      // v_pk_add_f32
  f32x2 r = (f32x2){__builtin_amdgcn_rcpf(d.x), __builtin_amdgcn_rcpf(d.y)};
  return v * r;                                           // v_pk_mul_f32
}
__device__ __forceinline__ void async16(const void* g, void* l){
  __builtin_amdgcn_global_load_lds(
      (const __attribute__((address_space(1))) unsigned int*)g,
      (__attribute__((address_space(3))) unsigned int*)l, 16, 0, 0);
}

// ---------------- prep_small: weight transposes -> bf16, b1e (513-block slices) -------
__global__ __launch_bounds__(256) void prep_small(
    const float* __restrict__ w_in, const float* __restrict__ w_out,
    const float* __restrict__ ew1, const float* __restrict__ ew2,
    const float* __restrict__ nw1, const float* __restrict__ nw2,
    const float* __restrict__ eb1,
    unsigned short* __restrict__ w_in_t, unsigned short* __restrict__ w_out_t,
    unsigned short* __restrict__ ew1cat, float* __restrict__ w1r,
    float* __restrict__ b1e,
    unsigned short* __restrict__ ew2t, unsigned short* __restrict__ nw1t,
    unsigned short* __restrict__ nw2t)
{
  const int s = blockIdx.y;
  const int tid = blockIdx.x * 256 + threadIdx.x;
  if (s == 18) {
    if (tid < NL * 512) {
      int l = tid >> 9, c = tid & 511;
      b1e[tid] = (c < 256) ? eb1[l * HD + c] : 0.0f;
    }
    return;
  }
  if (s >= 2 && s < 6) {
    int l = s - 2;
    if (tid >= 513 * HD) return;
    int k = tid / HD, n = tid - k * HD;
    float v = ew1[(size_t)l * 513 * HD + tid];
    if (k == 512) { w1r[l * HD + n] = v; return; }
    unsigned short* dst = ew1cat + (size_t)l * 512 * 256;
    if (k < 256) dst[(size_t)n * 256 + k] = f2bf(v);
    else         dst[(size_t)(256 + n) * 256 + (k - 256)] = f2bf(v);
    return;
  }
  const float* src; unsigned short* dst; int K, N;
  if (s == 0)      { src = w_in;  dst = w_in_t;  K = NF;   N = HD; }
  else if (s == 1) { src = w_out; dst = w_out_t; K = HD;   N = NF; }
  else if (s < 10) { int l = s-6;  src = ew2 + (size_t)l*HD*HD;   dst = ew2t + (size_t)l*HD*HD;  K = HD;   N = HD; }
  else if (s < 14) { int l = s-10; src = nw1 + (size_t)l*2*HD*HD; dst = nw1t + (size_t)l*HD*512; K = 2*HD; N = HD; }
  else             { int l = s-14; src = nw2 + (size_t)l*HD*HD;   dst = nw2t + (size_t)l*HD*HD;  K = HD;   N = HD; }
  if (tid >= K * N) return;
  int k = tid / N, n = tid - k * N;
  dst[(size_t)n * K + k] = f2bf(src[tid]);
}

// ---------------- prep_big: h->bf16, radial ----------------
__global__ __launch_bounds__(256) void prep_big(
    const float* __restrict__ h_in, const float* __restrict__ cd,
    unsigned short* __restrict__ hb_in, float* __restrict__ radial)
{
  const int s = blockIdx.y;
  const int tid = blockIdx.x * 256 + threadIdx.x;
  if (s == 0) {
    if (tid < NN * NF) hb_in[tid] = f2bf(h_in[tid]);
  } else {
    if (tid < NE) {
      float x = cd[tid*3+0], y = cd[tid*3+1], z = cd[tid*3+2];
      radial[tid] = x*x + y*y + z*z;
    }
  }
}

// ---------------- counting sort of edges by row (3-phase parallel scan) -------------
__global__ __launch_bounds__(256) void hist_k(const int* __restrict__ erow, int* __restrict__ hist){
  int e = blockIdx.x * 256 + threadIdx.x;
  if (e < NE){
    unsigned r = (unsigned)erow[e]; if (r >= NN) r = 0;
    atomicAdd(&hist[r], 1);
  }
}

__global__ __launch_bounds__(256) void scan1_k(const int* __restrict__ hist, int* __restrict__ bsum){
  __shared__ int red[256];
  const int t = threadIdx.x;
  const int bin = blockIdx.x * 256 + t;
  red[t] = (bin < NN) ? hist[bin] : 0;
  __syncthreads();
  for (int off = 128; off > 0; off >>= 1){
    if (t < off) red[t] += red[t + off];
    __syncthreads();
  }
  if (t == 0) bsum[blockIdx.x] = red[0];
}

__global__ __launch_bounds__(256) void scan2_k(const int* __restrict__ bsum, int* __restrict__ boff){
  __shared__ int part[256];
  const int t = threadIdx.x;
  int v = (t < NB) ? bsum[t] : 0;
  part[t] = v;
  __syncthreads();
  for (int off = 1; off < 256; off <<= 1){
    int p = (t >= off) ? part[t - off] : 0;
    __syncthreads();
    part[t] += p;
    __syncthreads();
  }
  if (t < NB) boff[t] = part[t] - v;   // exclusive
}

__global__ __launch_bounds__(256) void scan3_k(const int* __restrict__ hist,
                                               const int* __restrict__ boff,
                                               int* __restrict__ cursor){
  __shared__ int part[256];
  const int t = threadIdx.x;
  const int bin = blockIdx.x * 256 + t;
  int v = (bin < NN) ? hist[bin] : 0;
  part[t] = v;
  __syncthreads();
  for (int off = 1; off < 256; off <<= 1){
    int p = (t >= off) ? part[t - off] : 0;
    __syncthreads();
    part[t] += p;
    __syncthreads();
  }
  if (bin < NN) cursor[bin] = boff[blockIdx.x] + part[t] - v;   // exclusive
}

// scatter materializes (row,col) pairs and re-sorted radial at the sorted slot
__global__ __launch_bounds__(256) void scatter_k(const int* __restrict__ erow,
                                                 const int* __restrict__ ecol,
                                                 const float* __restrict__ radial,
                                                 int* __restrict__ cursor,
                                                 int* __restrict__ rowcol,
                                                 float* __restrict__ radial_s){
  int e = blockIdx.x * 256 + threadIdx.x;
  if (e < NE){
    unsigned r = (unsigned)erow[e]; if (r >= NN) r = 0;
    unsigned c = (unsigned)ecol[e]; if (c >= NN) c = 0;
    int pos = atomicAdd(&cursor[r], 1);
    rowcol[2*pos]   = (int)r;
    rowcol[2*pos+1] = (int)c;
    radial_s[pos] = radial[e];
  }
}

// ---------------- node0_k: hcur = hb@w_in^T+b_in; hT = hcur@ew1cat0^T+b1e0 ----------
// 32-row strips; A staged ONCE (kt-blocked); B read direct from L2 (no Bs, no
// per-kt barriers — each wave uses a disjoint quarter of B, LDS staging had
// zero sharing benefit). 2 barriers total.
__global__ __launch_bounds__(256, 4) void node0_k(
    const unsigned short* __restrict__ hb,      // [NN][64] bf16
    const unsigned short* __restrict__ w_in_t,  // [256][64]
    const float* __restrict__ b_in,
    const unsigned short* __restrict__ w1cat0,  // [512][256]
    const float* __restrict__ b1e0,             // [512]
    unsigned short* __restrict__ hcur,          // [NN][256] out
    unsigned short* __restrict__ hT)            // [NN][HTS] out
{
  __shared__ __align__(16) unsigned short LBUF[16384];   // 32 KB: lo=A(4KB), hi=strip(16KB)
  const int t = threadIdx.x;
  const int lane = t & 63, wave = t >> 6;
  const int ln15 = lane & 15, q = lane >> 4;
  const int bm = blockIdx.x;

  float bvin[4];
  #pragma unroll
  for (int j = 0; j < 4; ++j) bvin[j] = b_in[wave*64 + j*16 + ln15];

  // stage A strip [32][64] -> kt-blocked [2][32][32] (1 async16/thread)
  {
    const int ktb = t >> 7, rowhalf = (t >> 6) & 1, l = t & 63;
    async16(hb + (size_t)(bm*SR + rowhalf*16 + (l >> 2)) * NF + ktb*32 + (l & 3)*8,
            (char*)LBUF + ktb*2048 + rowhalf*1024 + l*16);
  }
  __syncthreads();

  f32x4 acc[2][4];
  #pragma unroll
  for (int i = 0; i < 2; ++i)
    #pragma unroll
    for (int j = 0; j < 4; ++j) acc[i][j] = (f32x4){0.f,0.f,0.f,0.f};

  // phase A: K = 64, B direct from global
  #pragma unroll
  for (int kt = 0; kt < 2; ++kt) {
    short8 fa[2], fb[4];
    #pragma unroll
    for (int i = 0; i < 2; ++i)
      fa[i] = *(const short8*)&LBUF[kt*1024 + (i*16 + ln15)*32 + q*8];
    #pragma unroll
    for (int j = 0; j < 4; ++j)
      fb[j] = *(const short8*)(w_in_t + (size_t)(wave*64 + j*16 + ln15) * NF + kt*32 + q*8);
    #pragma unroll
    for (int i = 0; i < 2; ++i)
      #pragma unroll
      for (int j = 0; j < 4; ++j)
        acc[i][j] = __builtin_amdgcn_mfma_f32_16x16x32_bf16(fa[i], fb[j], acc[i][j], 0, 0, 0);
  }

  // epilogue A: hcur -> global, strip -> LBUF hi (disjoint from lo A reads)
  #pragma unroll
  for (int i = 0; i < 2; ++i) {
    #pragma unroll
    for (int j = 0; j < 4; ++j) {
      const int n = wave*64 + j*16 + ln15;
      const int kt2 = n >> 5, k31 = n & 31;
      const int r0 = i*16 + q*4;
      const int m0 = bm*SR + r0;
      #pragma unroll
      for (int r = 0; r < 4; ++r) {
        unsigned short h = f2bf(acc[i][j][r] + bvin[j]);
        hcur[(size_t)(m0 + r) * HD + n] = h;
        LBUF[8192 + kt2*1024 + (r0 + r)*32 + k31] = h;
      }
    }
  }
  __syncthreads();

  // phase C: hT strip = strip @ w1cat0^T + b1e0 (B direct, no barriers)
  #pragma unroll
  for (int half = 0; half < 2; ++half) {
    #pragma unroll
    for (int i = 0; i < 2; ++i)
      #pragma unroll
      for (int j = 0; j < 4; ++j) acc[i][j] = (f32x4){0.f,0.f,0.f,0.f};
    for (int kt2 = 0; kt2 < 8; ++kt2) {
      short8 fa[2], fb[4];
      #pragma unroll
      for (int i = 0; i < 2; ++i)
        fa[i] = *(const short8*)&LBUF[8192 + kt2*1024 + (i*16 + ln15)*32 + q*8];
      #pragma unroll
      for (int j = 0; j < 4; ++j)
        fb[j] = *(const short8*)(w1cat0 + (size_t)(half*256 + wave*64 + j*16 + ln15) * 256 + kt2*32 + q*8);
      #pragma unroll
      for (int i = 0; i < 2; ++i)
        #pragma unroll
        for (int j = 0; j < 4; ++j)
          acc[i][j] = __builtin_amdgcn_mfma_f32_16x16x32_bf16(fa[i], fb[j], acc[i][j], 0, 0, 0);
    }
    #pragma unroll
    for (int i = 0; i < 2; ++i) {
      #pragma unroll
      for (int j = 0; j < 4; ++j) {
        const int n = half*256 + wave*64 + j*16 + ln15;
        const float bv = b1e0[n];
        #pragma unroll
        for (int r = 0; r < 4; ++r) {
          const int m = bm*SR + i*16 + q*4 + r;
          hT[(size_t)m * HTS + n] = f2bf(acc[i][j][r] + bv);
        }
      }
    }
  }
}

// ---------------- fused node MLP + next-layer hT (or final projection) ----------------
// 32-row strips (625 blocks). A staged once (kt-blocked, 32KB); B always direct
// from L2. 4 barriers total (was ~80 with per-kt Bs staging).
__global__ __launch_bounds__(256, 4) void node_k(
    unsigned short* __restrict__ hcur,      // [NN][256] bf16, read (k<256) + write
    float* __restrict__ aggF,               // [NN][256] fp32, read (k>=256) + zero
    const unsigned short* __restrict__ w1t, // [256][512]
    const float* __restrict__ b1,
    const unsigned short* __restrict__ w2t, // [256][256]
    const float* __restrict__ b2,
    const unsigned short* __restrict__ w1cat_next, // [512][256] or null
    const float* __restrict__ b1e_next,            // [512] or null
    unsigned short* __restrict__ hT,               // [NN][HTS] out (if w1cat_next)
    const unsigned short* __restrict__ w_out_t,    // [64][256] (used if last)
    const float* __restrict__ b_out,               // [64]
    float* __restrict__ outF)                      // [NN][64] fp32 (used if last)
{
  __shared__ __align__(16) unsigned short LBUF[16384];   // 32 KB
  const int t = threadIdx.x;
  const int lane = t & 63, wave = t >> 6;
  const int ln15 = lane & 15, q = lane >> 4;
  const int bm = blockIdx.x;

  float bv1[4], bv2[4];
  #pragma unroll
  for (int j = 0; j < 4; ++j) {
    bv1[j] = b1[wave*64 + j*16 + ln15];
    bv2[j] = b2[wave*64 + j*16 + ln15];
  }

  // ---- stage full A strip [32][512] kt-blocked [16][32][32] ----
  // hcur half (kt 0..7): 4 async16/thread, per-lane global rows
  #pragma unroll
  for (int s = 0; s < 4; ++s) {
    const int hbk = s*4 + wave;          // halfblock 0..15
    const int ktb = hbk >> 1, rowhalf = hbk & 1;
    const int l = lane;
    async16(hcur + (size_t)(bm*SR + rowhalf*16 + (l >> 2)) * HD + ktb*32 + (l & 3)*8,
            (char*)LBUF + ktb*2048 + rowhalf*1024 + l*16);
  }
  // agg half (kt 8..15): fp32 load + cvt + zero, 1 row x 32 cols per thread
  {
    const int row = t >> 3, kb = t & 7;
    float* p = aggF + (size_t)(bm*SR + row) * HD + kb*32;
    unsigned short* d = &LBUF[(8 + kb)*1024 + row*32];
    #pragma unroll
    for (int j2 = 0; j2 < 2; ++j2) {
      float4 a0 = *(const float4*)(p + j2*16);
      float4 a1 = *(const float4*)(p + j2*16 + 4);
      float4 a2 = *(const float4*)(p + j2*16 + 8);
      float4 a3 = *(const float4*)(p + j2*16 + 12);
      union { unsigned int u[8]; short8 s8[2]; } cv;
      cv.u[0] = pk2bf(a0.x, a0.y); cv.u[1] = pk2bf(a0.z, a0.w);
      cv.u[2] = pk2bf(a1.x, a1.y); cv.u[3] = pk2bf(a1.z, a1.w);
      cv.u[4] = pk2bf(a2.x, a2.y); cv.u[5] = pk2bf(a2.z, a2.w);
      cv.u[6] = pk2bf(a3.x, a3.y); cv.u[7] = pk2bf(a3.z, a3.w);
      *(short8*)(d + j2*16)     = cv.s8[0];
      *(short8*)(d + j2*16 + 8) = cv.s8[1];
      *(float4*)(p + j2*16)      = float4{0.f,0.f,0.f,0.f};
      *(float4*)(p + j2*16 + 4)  = float4{0.f,0.f,0.f,0.f};
      *(float4*)(p + j2*16 + 8)  = float4{0.f,0.f,0.f,0.f};
      *(float4*)(p + j2*16 + 12) = float4{0.f,0.f,0.f,0.f};
    }
  }
  __syncthreads();                                        // barrier 1

  f32x4 acc[2][4];
  #pragma unroll
  for (int i = 0; i < 2; ++i)
    #pragma unroll
    for (int j = 0; j < 4; ++j) acc[i][j] = (f32x4){0.f,0.f,0.f,0.f};

  // ---- phase A: K = 512, barrier-free ----
  for (int kt = 0; kt < 16; ++kt) {
    short8 fa[2], fb[4];
    #pragma unroll
    for (int i = 0; i < 2; ++i)
      fa[i] = *(const short8*)&LBUF[kt*1024 + (i*16 + ln15)*32 + q*8];
    #pragma unroll
    for (int j = 0; j < 4; ++j)
      fb[j] = *(const short8*)(w1t + (size_t)(wave*64 + j*16 + ln15) * 512 + kt*32 + q*8);
    #pragma unroll
    for (int i = 0; i < 2; ++i)
      #pragma unroll
      for (int j = 0; j < 4; ++j)
        acc[i][j] = __builtin_amdgcn_mfma_f32_16x16x32_bf16(fa[i], fb[j], acc[i][j], 0, 0, 0);
  }
  __syncthreads();                                        // barrier 2 (A dead)

  // x1 = silu(acc + b1) -> LBUF lo [kt2][row][k31]
  #pragma unroll
  for (int i = 0; i < 2; ++i) {
    #pragma unroll
    for (int j = 0; j < 4; ++j) {
      const int k = wave*64 + j*16 + ln15;
      const int kt2 = k >> 5, k31 = k & 31;
      const f32x2 bb = (f32x2){bv1[j], bv1[j]};
      f32x2 s01 = (f32x2){acc[i][j][0], acc[i][j][1]} + bb;
      f32x2 s23 = (f32x2){acc[i][j][2], acc[i][j][3]} + bb;
      f32x2 r01 = silu2(s01);
      f32x2 r23 = silu2(s23);
      const int r0 = i*16 + q*4;
      LBUF[kt2*1024 + (r0  )*32 + k31] = f2bf(r01.x);
      LBUF[kt2*1024 + (r0+1)*32 + k31] = f2bf(r01.y);
      LBUF[kt2*1024 + (r0+2)*32 + k31] = f2bf(r23.x);
      LBUF[kt2*1024 + (r0+3)*32 + k31] = f2bf(r23.y);
    }
  }
  #pragma unroll
  for (int i = 0; i < 2; ++i)
    #pragma unroll
    for (int j = 0; j < 4; ++j) acc[i][j] = (f32x4){0.f,0.f,0.f,0.f};
  __syncthreads();                                        // barrier 3

  // ---- phase B: K = 256, barrier-free ----
  for (int kt2 = 0; kt2 < 8; ++kt2) {
    short8 fa[2], fb[4];
    #pragma unroll
    for (int i = 0; i < 2; ++i)
      fa[i] = *(const short8*)&LBUF[kt2*1024 + (i*16 + ln15)*32 + q*8];
    #pragma unroll
    for (int j = 0; j < 4; ++j)
      fb[j] = *(const short8*)(w2t + (size_t)(wave*64 + j*16 + ln15) * 256 + kt2*32 + q*8);
    #pragma unroll
    for (int i = 0; i < 2; ++i)
      #pragma unroll
      for (int j = 0; j < 4; ++j)
        acc[i][j] = __builtin_amdgcn_mfma_f32_16x16x32_bf16(fa[i], fb[j], acc[i][j], 0, 0, 0);
  }

  // epilogue B: hcur -> global, strip -> LBUF hi (disjoint from lo x1 reads)
  #pragma unroll
  for (int i = 0; i < 2; ++i) {
    #pragma unroll
    for (int j = 0; j < 4; ++j) {
      const int n = wave*64 + j*16 + ln15;
      const int kt2 = n >> 5, k31 = n & 31;
      const int r0 = i*16 + q*4;
      const int m0 = bm*SR + r0;
      #pragma unroll
      for (int r = 0; r < 4; ++r) {
        unsigned short h = f2bf(acc[i][j][r] + bv2[j]);
        hcur[(size_t)(m0 + r) * HD + n] = h;
        LBUF[8192 + kt2*1024 + (r0 + r)*32 + k31] = h;
      }
    }
  }
  __syncthreads();                                        // barrier 4

  if (w1cat_next) {
    // ---- phase C: hT strip = strip @ ew1cat_next^T + b1e_next, barrier-free ----
    #pragma unroll
    for (int half = 0; half < 2; ++half) {
      #pragma unroll
      for (int i = 0; i < 2; ++i)
        #pragma unroll
        for (int j = 0; j < 4; ++j) acc[i][j] = (f32x4){0.f,0.f,0.f,0.f};
      for (int kt2 = 0; kt2 < 8; ++kt2) {
        short8 fa[2], fb[4];
        #pragma unroll
        for (int i = 0; i < 2; ++i)
          fa[i] = *(const short8*)&LBUF[8192 + kt2*1024 + (i*16 + ln15)*32 + q*8];
        #pragma unroll
        for (int j = 0; j < 4; ++j)
          fb[j] = *(const short8*)(w1cat_next + (size_t)(half*256 + wave*64 + j*16 + ln15) * 256 + kt2*32 + q*8);
        #pragma unroll
        for (int i = 0; i < 2; ++i)
          #pragma unroll
          for (int j = 0; j < 4; ++j)
            acc[i][j] = __builtin_amdgcn_mfma_f32_16x16x32_bf16(fa[i], fb[j], acc[i][j], 0, 0, 0);
      }
      #pragma unroll
      for (int i = 0; i < 2; ++i) {
        #pragma unroll
        for (int j = 0; j < 4; ++j) {
          const int n = half*256 + wave*64 + j*16 + ln15;
          const float bv = b1e_next[n];
          #pragma unroll
          for (int r = 0; r < 4; ++r) {
            const int m = bm*SR + i*16 + q*4 + r;
            hT[(size_t)m * HTS + n] = f2bf(acc[i][j][r] + bv);
          }
        }
      }
    }
  } else {
    // ---- phase D: out = strip @ w_out^T + b_out (N=64, fp32), barrier-free ----
    const int nD = wave*16 + ln15;             // 0..63
    const float bvD = b_out[nD];
    f32x4 accD[2];
    accD[0] = (f32x4){0.f,0.f,0.f,0.f};
    accD[1] = (f32x4){0.f,0.f,0.f,0.f};
    for (int kt2 = 0; kt2 < 8; ++kt2) {
      short8 fa[2];
      #pragma unroll
      for (int i = 0; i < 2; ++i)
        fa[i] = *(const short8*)&LBUF[8192 + kt2*1024 + (i*16 + ln15)*32 + q*8];
      short8 fb = *(const short8*)(w_out_t + (size_t)nD * 256 + kt2*32 + q*8);
      #pragma unroll
      for (int i = 0; i < 2; ++i)
        accD[i] = __builtin_amdgcn_mfma_f32_16x16x32_bf16(fa[i], fb, accD[i], 0, 0, 0);
    }
    #pragma unroll
    for (int i = 0; i < 2; ++i) {
      #pragma unroll
      for (int r = 0; r < 4; ++r) {
        const int m = bm*SR + i*16 + q*4 + r;
        outF[(size_t)m * NF + nD] = accD[i][r] + bvD;
      }
    }
  }
}

// ---------------- fused edge MLP + aggregation (bf16 hT, stride-640 destagger) --------
__global__ __launch_bounds__(256, 4) void edge_k(
    const unsigned short* __restrict__ hT,   // [NN][HTS] bf16, cols 0..511 valid
    const int* __restrict__ rowcol,          // [NE][2] sorted (row,col)
    const float* __restrict__ radial_s,      // [NE] sorted radial
    const float* __restrict__ w1r,           // [256]
    const unsigned short* __restrict__ w2t,  // [256][256]
    const float* __restrict__ b2,
    float* __restrict__ agg)                  // [NN][256] fp32, pre-zeroed
{
  __shared__ __align__(16) unsigned short MBUF[16896];   // 33.8 KB
  __shared__ int   rowS[64];
  __shared__ float w1rS[256];
  unsigned short* M1  = MBUF;
  unsigned short* m2T = MBUF;

  const int t = threadIdx.x;
  const int lane = t & 63, wave = t >> 6;
  const int ln15 = lane & 15, q = lane >> 4;
  // chunked XCD swizzle: XCD k owns a contiguous 1/8 of sorted-edge space (hr L2 reuse)
  int blk = blockIdx.x;
  blk = (blk & 7) * ((int)gridDim.x >> 3) + (blk >> 3);
  const int e0 = blk * 64;
  const int sr = t >> 2;
  const int sc_swz = (((t & 3) ^ ((sr >> 1) & 3))) * 8;
  const int xq = ((q ^ ((ln15 >> 1) & 3))) * 8;

  // early small loads (before the 16 gathers: vmcnt retires in issue order)
  const int2 rc = *(const int2*)(rowcol + 2*(e0 + sr));   // gather base (1 load)
  int rowv = 0;
  if (t < 64) rowv = rowcol[2*(e0 + t)];
  const float w1v = w1r[t];
  const float rad = radial_s[e0 + sr];

  float bv2[4];
  #pragma unroll
  for (int j = 0; j < 4; ++j) bv2[j] = b2[wave*64 + j*16 + ln15];

  const unsigned short* hr = hT + (size_t)rc.x * HTS + sc_swz;
  const unsigned short* hc = hT + (size_t)rc.y * HTS + 256 + sc_swz;

  // batch all 16 gather b128s into registers, interleaved
  short8 va[8], vb[8];
  #pragma unroll
  for (int ch = 0; ch < 8; ++ch) {
    va[ch] = *(const short8*)(hr + ch*32);
    vb[ch] = *(const short8*)(hc + ch*32);
  }

  if (t < 64) rowS[t] = rowv;
  w1rS[t] = w1v;

  const unsigned short* w2row[4];
  #pragma unroll
  for (int j = 0; j < 4; ++j)
    w2row[j] = w2t + (size_t)(wave*64 + j*16 + ln15) * HD + q*8;

  __syncthreads();

  // prologue: m1 = silu(hr + hc + rad*w1r) -> M1 (kt-blocked, swizzled), b128 stores
  const f32x2 rad2 = (f32x2){rad, rad};
  #pragma unroll
  for (int ch = 0; ch < 8; ++ch) {
    const int c0 = ch*32 + sc_swz;
    const unsigned int* ua = (const unsigned int*)&va[ch];
    const unsigned int* ub = (const unsigned int*)&vb[ch];
    union { unsigned int u[4]; short8 s; } res;
    #pragma unroll
    for (int i = 0; i < 4; ++i) {
      union { unsigned int i; float f; } alo, ahi, blo, bhi;
      alo.i = ua[i] << 16; ahi.i = ua[i] & 0xFFFF0000u;
      blo.i = ub[i] << 16; bhi.i = ub[i] & 0xFFFF0000u;
      f32x2 av = (f32x2){alo.f, ahi.f};
      f32x2 bv = (f32x2){blo.f, bhi.f};
      f32x2 wv = *(const f32x2*)&w1rS[c0 + 2*i];
      f32x2 o = av + bv;
      o = o + rad2 * wv;            // pk fma
      f32x2 sv = silu2(o);
      res.u[i] = pk2bf(sv.x, sv.y);
    }
    *(short8*)&M1[ch*2048 + sr*32 + (t & 3)*8] = res.s;
  }
  __syncthreads();

  // phase 2: K = 256 (M1 @ W2^T); fb direct from global (L2-resident w2t)
  f32x4 acc2[4][4];
  #pragma unroll
  for (int i = 0; i < 4; ++i)
    #pragma unroll
    for (int j = 0; j < 4; ++j) acc2[i][j] = (f32x4){0.f,0.f,0.f,0.f};

  __builtin_amdgcn_s_setprio(1);
  #pragma unroll
  for (int kt = 0; kt < 8; ++kt) {
    short8 fa[4], fb[4];
    #pragma unroll
    for (int j = 0; j < 4; ++j) fb[j] = *(const short8*)(w2row[j] + kt*32);
    #pragma unroll
    for (int i = 0; i < 4; ++i) fa[i] = *(const short8*)&M1[kt*2048 + (i*16 + ln15)*32 + xq];
    #pragma unroll
    for (int i = 0; i < 4; ++i)
      #pragma unroll
      for (int j = 0; j < 4; ++j)
        acc2[i][j] = __builtin_amdgcn_mfma_f32_16x16x32_bf16(fa[i], fb[j], acc2[i][j], 0, 0, 0);
  }
  __builtin_amdgcn_s_setprio(0);
  __syncthreads();

  // epilogue 2a: silu -> m2T[col][stride 66] in LDS (pk math)
  #pragma unroll
  for (int i = 0; i < 4; ++i) {
    #pragma unroll
    for (int j = 0; j < 4; ++j) {
      const int n = wave*64 + j*16 + ln15;
      const f32x2 b2v = (f32x2){bv2[j], bv2[j]};
      f32x2 s01 = (f32x2){acc2[i][j][0], acc2[i][j][1]} + b2v;
      f32x2 s23 = (f32x2){acc2[i][j][2], acc2[i][j][3]} + b2v;
      f32x2 r01 = silu2(s01);
      f32x2 r23 = silu2(s23);
      const int m = i*16 + q*4;
      *(unsigned int*)&m2T[n*66 + m]     = pk2bf(r01.x, r01.y);
      *(unsigned int*)&m2T[n*66 + m + 2] = pk2bf(r23.x, r23.y);
    }
  }
  __syncthreads();

  // epilogue 2b: per-column segmented reduction (rowS readfirstlane -> scalar cmps)
  {
    const int c = t;
    int cur = __builtin_amdgcn_readfirstlane(rowS[0]);
    float s = 0.f;
    #pragma unroll
    for (int m = 0; m < 64; m += 4) {
      unsigned int u0 = *(const unsigned int*)&m2T[c*66 + m];
      unsigned int u1 = *(const unsigned int*)&m2T[c*66 + m + 2];
      int n0 = __builtin_amdgcn_readfirstlane(rowS[m]);
      int n1 = __builtin_amdgcn_readfirstlane(rowS[m+1]);
      int n2 = __builtin_amdgcn_readfirstlane(rowS[m+2]);
      int n3 = __builtin_amdgcn_readfirstlane(rowS[m+3]);
      float f0 = bf2f((unsigned short)u0), f1 = bf2f((unsigned short)(u0 >> 16));
      float f2v = bf2f((unsigned short)u1), f3 = bf2f((unsigned short)(u1 >> 16));
      if (n0 != cur) { atomicAdd(&agg[(size_t)cur * HD + c], s); s = 0.f; cur = n0; }
      s += f0;
      if (n1 != cur) { atomicAdd(&agg[(size_t)cur * HD + c], s); s = 0.f; cur = n1; }
      s += f1;
      if (n2 != cur) { atomicAdd(&agg[(size_t)cur * HD + c], s); s = 0.f; cur = n2; }
      s += f2v;
      if (n3 != cur) { atomicAdd(&agg[(size_t)cur * HD + c], s); s = 0.f; cur = n3; }
      s += f3;
    }
    atomicAdd(&agg[(size_t)cur * HD + c], s);
  }
}

// ---------------- launch ----------------
extern "C" void kernel_launch(void* const* d_in, const int* in_sizes, int n_in,
                              void* d_out, int out_size, void* d_ws, size_t ws_size,
                              hipStream_t stream)
{
  (void)in_sizes; (void)n_in; (void)out_size; (void)ws_size;
  const float* h_in  = (const float*)d_in[0];
  const int*   ei    = (const int*)d_in[1];
  const float* cd    = (const float*)d_in[2];
  const float* w_in  = (const float*)d_in[3];
  const float* b_in  = (const float*)d_in[4];
  const float* w_out = (const float*)d_in[5];
  const float* b_out = (const float*)d_in[6];
  const float* ew1   = (const float*)d_in[7];
  const float* eb1   = (const float*)d_in[8];
  const float* ew2   = (const float*)d_in[9];
  const float* eb2   = (const float*)d_in[10];
  const float* nw1   = (const float*)d_in[11];
  const float* nb1   = (const float*)d_in[12];
  const float* nw2   = (const float*)d_in[13];
  const float* nb2   = (const float*)d_in[14];
  float* out = (float*)d_out;

  char* base = (char*)d_ws;
  size_t off = 0;
  auto WS = [&](size_t bytes) -> char* {
    char* p = base + off;
    off = (off + bytes + 255) & ~(size_t)255;
    return p;
  };
  float*          radial  = (float*)WS((size_t)NE * 4);
  unsigned short* hb_in   = (unsigned short*)WS((size_t)NN * NF * 2);
  unsigned short* hcur    = (unsigned short*)WS((size_t)NN * HD * 2);
  float*          aggF    = (float*)WS((size_t)NN * HD * 4);
  unsigned short* hT      = (unsigned short*)WS((size_t)NN * HTS * 2);  // 25.6 MB bf16
  unsigned short* w_in_t  = (unsigned short*)WS((size_t)NF * HD * 2);
  unsigned short* w_out_t = (unsigned short*)WS((size_t)NF * HD * 2);
  unsigned short* ew1cat  = (unsigned short*)WS((size_t)NL * 512 * 256 * 2);
  float*          w1r     = (float*)WS((size_t)NL * HD * 4);
  float*          b1e     = (float*)WS((size_t)NL * 512 * 4);
  unsigned short* ew2t    = (unsigned short*)WS((size_t)NL * HD * HD * 2);
  unsigned short* nw1t    = (unsigned short*)WS((size_t)NL * HD * 512 * 2);
  unsigned short* nw2t    = (unsigned short*)WS((size_t)NL * HD * HD * 2);
  int*            hist    = (int*)WS((size_t)NN * 4);
  int*            bsum    = (int*)WS((size_t)128 * 4);
  int*            boff    = (int*)WS((size_t)128 * 4);
  int*            cursor  = (int*)WS((size_t)NN * 4);
  int*            rowcol  = (int*)WS((size_t)NE * 2 * 4);
  float*          radial_s= (float*)WS((size_t)NE * 4);

  hipMemsetAsync(hist, 0, (size_t)NN * 4, stream);
  hipMemsetAsync(aggF, 0, (size_t)NN * HD * 4, stream);
  prep_small<<<dim3(513, 19), 256, 0, stream>>>(w_in, w_out, ew1, ew2, nw1, nw2, eb1,
      w_in_t, w_out_t, ew1cat, w1r, b1e, ew2t, nw1t, nw2t);
  prep_big<<<dim3(5000, 2), 256, 0, stream>>>(h_in, cd, hb_in, radial);
  hist_k<<<NE / 256, 256, 0, stream>>>(ei, hist);
  scan1_k<<<NB, 256, 0, stream>>>(hist, bsum);
  scan2_k<<<1, 256, 0, stream>>>(bsum, boff);
  scan3_k<<<NB, 256, 0, stream>>>(hist, boff, cursor);
  scatter_k<<<NE / 256, 256, 0, stream>>>(ei, ei + NE, radial, cursor, rowcol, radial_s);

  // embedding + layer-0 hT table, fused per 32-row strip
  node0_k<<<NN / SR, 256, 0, stream>>>(hb_in, w_in_t, b_in, ew1cat, b1e, hcur, hT);

  for (int l = 0; l < NL; ++l) {
    edge_k<<<NE / 64, 256, 0, stream>>>(hT, rowcol, radial_s,
        w1r + l * HD, ew2t + (size_t)l * HD * HD, eb2 + l * HD, aggF);
    const int last = (l == NL - 1);
    node_k<<<NN / SR, 256, 0, stream>>>(hcur, aggF,
        nw1t + (size_t)l * HD * 512, nb1 + l * HD,
        nw2t + (size_t)l * HD * HD, nb2 + l * HD,
        last ? nullptr : (ew1cat + (size_t)(l+1) * 512 * 256),
        last ? nullptr : (b1e + (size_t)(l+1) * 512),
        hT, w_out_t, b_out, out);
  }
}

// Round 10
// 1104.461 us; speedup vs baseline: 1.1283x; 1.1283x over previous
//
#include <hip/hip_runtime.h>
#include <hip/hip_bf16.h>
#include <cstdint>
#include <cstddef>

#define NN 20000
#define NE 640000
#define NF 64
#define HD 256
#define NL 4
#define HTS 640   // hT row stride in shorts: 1280 B = 5x256 B (destaggers HBM channels)
#define SR 32     // node strip rows (R7-proven; SR=16 doubled weight traffic, B-direct exposed L2 latency)
#define NB 79     // scan blocks: ceil(NN/256)

typedef __attribute__((ext_vector_type(8))) short short8;
typedef __attribute__((ext_vector_type(4))) float f32x4;
typedef __attribute__((ext_vector_type(2))) float f32x2;

__device__ __forceinline__ float bf2f(unsigned short u){
  union { unsigned int i; float f; } x; x.i = ((unsigned int)u) << 16; return x.f;
}
__device__ __forceinline__ unsigned short f2bf(float f){
  union { float f; unsigned int i; } x; x.f = f;
  unsigned int r = x.i + 0x7FFFu + ((x.i >> 16) & 1u);   // RNE
  return (unsigned short)(r >> 16);
}
// packed 2xf32 -> 2xbf16 (v_cvt_pk_bf16_f32 on gfx950, RNE)
__device__ __forceinline__ unsigned int pk2bf(float a, float b){
  union { __hip_bfloat162 h; unsigned int u; } cv;
  cv.h = __float22bfloat162_rn(float2{a, b});
  return cv.u;
}
// silu via guaranteed-native v_exp_f32 + v_rcp_f32
__device__ __forceinline__ float silu_f(float v){
  float e = __builtin_amdgcn_exp2f(v * -1.442695041f);
  return v * __builtin_amdgcn_rcpf(1.0f + e);
}
// packed silu on 2 lanes: pk mul/add around the 2 scalar trans ops
__device__ __forceinline__ f32x2 silu2(f32x2 v){
  f32x2 t = v * (f32x2){-1.442695041f, -1.442695041f};   // v_pk_mul_f32
  f32x2 e = (f32x2){__builtin_amdgcn_exp2f(t.x), __builtin_amdgcn_exp2f(t.y)};
  f32x2 d = e + (f32x2){1.0f, 1.0f};                      // v_pk_add_f32
  f32x2 r = (f32x2){__builtin_amdgcn_rcpf(d.x), __builtin_amdgcn_rcpf(d.y)};
  return v * r;                                           // v_pk_mul_f32
}
__device__ __forceinline__ void async16(const void* g, void* l){
  __builtin_amdgcn_global_load_lds(
      (const __attribute__((address_space(1))) unsigned int*)g,
      (__attribute__((address_space(3))) unsigned int*)l, 16, 0, 0);
}

// ---------------- prep_small: weight transposes -> bf16, b1e (513-block slices) -------
__global__ __launch_bounds__(256) void prep_small(
    const float* __restrict__ w_in, const float* __restrict__ w_out,
    const float* __restrict__ ew1, const float* __restrict__ ew2,
    const float* __restrict__ nw1, const float* __restrict__ nw2,
    const float* __restrict__ eb1,
    unsigned short* __restrict__ w_in_t, unsigned short* __restrict__ w_out_t,
    unsigned short* __restrict__ ew1cat, float* __restrict__ w1r,
    float* __restrict__ b1e,
    unsigned short* __restrict__ ew2t, unsigned short* __restrict__ nw1t,
    unsigned short* __restrict__ nw2t)
{
  const int s = blockIdx.y;
  const int tid = blockIdx.x * 256 + threadIdx.x;
  if (s == 18) {
    if (tid < NL * 512) {
      int l = tid >> 9, c = tid & 511;
      b1e[tid] = (c < 256) ? eb1[l * HD + c] : 0.0f;
    }
    return;
  }
  if (s >= 2 && s < 6) {
    int l = s - 2;
    if (tid >= 513 * HD) return;
    int k = tid / HD, n = tid - k * HD;
    float v = ew1[(size_t)l * 513 * HD + tid];
    if (k == 512) { w1r[l * HD + n] = v; return; }
    unsigned short* dst = ew1cat + (size_t)l * 512 * 256;
    if (k < 256) dst[(size_t)n * 256 + k] = f2bf(v);
    else         dst[(size_t)(256 + n) * 256 + (k - 256)] = f2bf(v);
    return;
  }
  const float* src; unsigned short* dst; int K, N;
  if (s == 0)      { src = w_in;  dst = w_in_t;  K = NF;   N = HD; }
  else if (s == 1) { src = w_out; dst = w_out_t; K = HD;   N = NF; }
  else if (s < 10) { int l = s-6;  src = ew2 + (size_t)l*HD*HD;   dst = ew2t + (size_t)l*HD*HD;  K = HD;   N = HD; }
  else if (s < 14) { int l = s-10; src = nw1 + (size_t)l*2*HD*HD; dst = nw1t + (size_t)l*HD*512; K = 2*HD; N = HD; }
  else             { int l = s-14; src = nw2 + (size_t)l*HD*HD;   dst = nw2t + (size_t)l*HD*HD;  K = HD;   N = HD; }
  if (tid >= K * N) return;
  int k = tid / N, n = tid - k * N;
  dst[(size_t)n * K + k] = f2bf(src[tid]);
}

// ---------------- prep_big: h->bf16, radial ----------------
__global__ __launch_bounds__(256) void prep_big(
    const float* __restrict__ h_in, const float* __restrict__ cd,
    unsigned short* __restrict__ hb_in, float* __restrict__ radial)
{
  const int s = blockIdx.y;
  const int tid = blockIdx.x * 256 + threadIdx.x;
  if (s == 0) {
    if (tid < NN * NF) hb_in[tid] = f2bf(h_in[tid]);
  } else {
    if (tid < NE) {
      float x = cd[tid*3+0], y = cd[tid*3+1], z = cd[tid*3+2];
      radial[tid] = x*x + y*y + z*z;
    }
  }
}

// ---------------- counting sort of edges by row (3-phase parallel scan) -------------
__global__ __launch_bounds__(256) void hist_k(const int* __restrict__ erow, int* __restrict__ hist){
  int e = blockIdx.x * 256 + threadIdx.x;
  if (e < NE){
    unsigned r = (unsigned)erow[e]; if (r >= NN) r = 0;
    atomicAdd(&hist[r], 1);
  }
}

__global__ __launch_bounds__(256) void scan1_k(const int* __restrict__ hist, int* __restrict__ bsum){
  __shared__ int red[256];
  const int t = threadIdx.x;
  const int bin = blockIdx.x * 256 + t;
  red[t] = (bin < NN) ? hist[bin] : 0;
  __syncthreads();
  for (int off = 128; off > 0; off >>= 1){
    if (t < off) red[t] += red[t + off];
    __syncthreads();
  }
  if (t == 0) bsum[blockIdx.x] = red[0];
}

__global__ __launch_bounds__(256) void scan2_k(const int* __restrict__ bsum, int* __restrict__ boff){
  __shared__ int part[256];
  const int t = threadIdx.x;
  int v = (t < NB) ? bsum[t] : 0;
  part[t] = v;
  __syncthreads();
  for (int off = 1; off < 256; off <<= 1){
    int p = (t >= off) ? part[t - off] : 0;
    __syncthreads();
    part[t] += p;
    __syncthreads();
  }
  if (t < NB) boff[t] = part[t] - v;   // exclusive
}

__global__ __launch_bounds__(256) void scan3_k(const int* __restrict__ hist,
                                               const int* __restrict__ boff,
                                               int* __restrict__ cursor){
  __shared__ int part[256];
  const int t = threadIdx.x;
  const int bin = blockIdx.x * 256 + t;
  int v = (bin < NN) ? hist[bin] : 0;
  part[t] = v;
  __syncthreads();
  for (int off = 1; off < 256; off <<= 1){
    int p = (t >= off) ? part[t - off] : 0;
    __syncthreads();
    part[t] += p;
    __syncthreads();
  }
  if (bin < NN) cursor[bin] = boff[blockIdx.x] + part[t] - v;   // exclusive
}

// scatter materializes (row,col) pairs and re-sorted radial at the sorted slot
__global__ __launch_bounds__(256) void scatter_k(const int* __restrict__ erow,
                                                 const int* __restrict__ ecol,
                                                 const float* __restrict__ radial,
                                                 int* __restrict__ cursor,
                                                 int* __restrict__ rowcol,
                                                 float* __restrict__ radial_s){
  int e = blockIdx.x * 256 + threadIdx.x;
  if (e < NE){
    unsigned r = (unsigned)erow[e]; if (r >= NN) r = 0;
    unsigned c = (unsigned)ecol[e]; if (c >= NN) c = 0;
    int pos = atomicAdd(&cursor[r], 1);
    rowcol[2*pos]   = (int)r;
    rowcol[2*pos+1] = (int)c;
    radial_s[pos] = radial[e];
  }
}

// ---------------- node0_k: hcur = hb@w_in^T+b_in; hT = hcur@ew1cat0^T+b1e0 ----------
// R7-proven: 32-row strips; Bs staged via async16 (pipelined); strip in LDS.
__global__ __launch_bounds__(256, 4) void node0_k(
    const unsigned short* __restrict__ hb,      // [NN][64] bf16
    const unsigned short* __restrict__ w_in_t,  // [256][64]
    const float* __restrict__ b_in,
    const unsigned short* __restrict__ w1cat0,  // [512][256]
    const float* __restrict__ b1e0,             // [512]
    unsigned short* __restrict__ hcur,          // [NN][256] out
    unsigned short* __restrict__ hT)            // [NN][HTS] out
{
  __shared__ __align__(16) unsigned short As[SR*64];      // 4 KB
  __shared__ __align__(16) unsigned short Bs[256*32];     // 16 KB
  __shared__ __align__(16) unsigned short xL[8*SR*32];    // 16 KB (hcur strip)
  const int t = threadIdx.x;
  const int lane = t & 63, wave = t >> 6;
  const int ln15 = lane & 15, q = lane >> 4;
  const int bm = blockIdx.x;
  const int sc = (t & 3) * 8;
  const int srB = t >> 2;              // 0..63

  float bvin[4];
  #pragma unroll
  for (int j = 0; j < 4; ++j) bvin[j] = b_in[wave*64 + j*16 + ln15];

  f32x4 acc[2][4];
  #pragma unroll
  for (int i = 0; i < 2; ++i)
    #pragma unroll
    for (int j = 0; j < 4; ++j) acc[i][j] = (f32x4){0.f,0.f,0.f,0.f};

  // stage A strip once: [32][64] bf16
  async16(hb + (size_t)(bm*SR + (t >> 3)) * NF + (t & 7)*8, &As[t*8]);

  // ---------- phase A: K = 64, hcur_strip = hb_strip @ w_in_t^T + b_in ----------
  for (int kt = 0; kt < 2; ++kt) {
    #pragma unroll
    for (int i = 0; i < 4; ++i)
      async16(w_in_t + (size_t)(i*64 + srB) * NF + kt*32 + sc, &Bs[i*2048 + t*8]);
    __syncthreads();
    short8 fa[2], fb[4];
    #pragma unroll
    for (int i = 0; i < 2; ++i) fa[i] = *(const short8*)&As[(i*16 + ln15)*64 + kt*32 + q*8];
    #pragma unroll
    for (int j = 0; j < 4; ++j) fb[j] = *(const short8*)&Bs[(wave*64 + j*16 + ln15)*32 + q*8];
    #pragma unroll
    for (int i = 0; i < 2; ++i)
      #pragma unroll
      for (int j = 0; j < 4; ++j)
        acc[i][j] = __builtin_amdgcn_mfma_f32_16x16x32_bf16(fa[i], fb[j], acc[i][j], 0, 0, 0);
    __syncthreads();
  }

  // epilogue A: hcur = acc + b_in (no silu) -> global + xL
  #pragma unroll
  for (int i = 0; i < 2; ++i) {
    #pragma unroll
    for (int j = 0; j < 4; ++j) {
      const int n = wave*64 + j*16 + ln15;
      const int kt2 = n >> 5, k31 = n & 31;
      const int r0 = i*16 + q*4;
      const int m0 = bm*SR + r0;
      #pragma unroll
      for (int r = 0; r < 4; ++r) {
        unsigned short h = f2bf(acc[i][j][r] + bvin[j]);
        hcur[(size_t)(m0 + r) * HD + n] = h;
        xL[kt2*1024 + (r0 + r)*32 + k31] = h;
      }
    }
  }

  // ---------- phase C: hT strip = hcur_strip @ w1cat0^T + b1e0 ----------
  #pragma unroll
  for (int half = 0; half < 2; ++half) {
    #pragma unroll
    for (int i = 0; i < 2; ++i)
      #pragma unroll
      for (int j = 0; j < 4; ++j) acc[i][j] = (f32x4){0.f,0.f,0.f,0.f};
    for (int kt2 = 0; kt2 < 8; ++kt2) {
      #pragma unroll
      for (int i = 0; i < 4; ++i)
        async16(w1cat0 + (size_t)(half*256 + i*64 + srB) * 256 + kt2*32 + sc,
                &Bs[i*2048 + t*8]);
      __syncthreads();
      short8 fa[2], fb[4];
      #pragma unroll
      for (int i = 0; i < 2; ++i) fa[i] = *(const short8*)&xL[kt2*1024 + (i*16 + ln15)*32 + q*8];
      #pragma unroll
      for (int j = 0; j < 4; ++j) fb[j] = *(const short8*)&Bs[(wave*64 + j*16 + ln15)*32 + q*8];
      #pragma unroll
      for (int i = 0; i < 2; ++i)
        #pragma unroll
        for (int j = 0; j < 4; ++j)
          acc[i][j] = __builtin_amdgcn_mfma_f32_16x16x32_bf16(fa[i], fb[j], acc[i][j], 0, 0, 0);
      __syncthreads();
    }
    #pragma unroll
    for (int i = 0; i < 2; ++i) {
      #pragma unroll
      for (int j = 0; j < 4; ++j) {
        const int n = half*256 + wave*64 + j*16 + ln15;
        const float bv = b1e0[n];
        #pragma unroll
        for (int r = 0; r < 4; ++r) {
          const int m = bm*SR + i*16 + q*4 + r;
          hT[(size_t)m * HTS + n] = f2bf(acc[i][j][r] + bv);
        }
      }
    }
  }
}

// ---------------- fused node MLP + next-layer hT (or final projection) ----------------
// R7-proven: 32-row strips (625 blocks), Bs staged via async16.
// A: x1 = silu([hcur|bf16(agg)] @ W1^T + b1)   (x1 in LDS only; agg strip zeroed)
// B: hcur = x1 @ W2^T + b2                     (in-place; strip also kept in LDS)
// C: hT = hcur_strip @ ew1cat_next^T + b1e_next   (layers 0..NL-2)
// D: out = hcur_strip @ w_out^T + b_out, fp32     (last layer)
__global__ __launch_bounds__(256, 4) void node_k(
    unsigned short* __restrict__ hcur,      // [NN][256] bf16, read (k<256) + write
    float* __restrict__ aggF,               // [NN][256] fp32, read (k>=256) + zero
    const unsigned short* __restrict__ w1t, // [256][512]
    const float* __restrict__ b1,
    const unsigned short* __restrict__ w2t, // [256][256]
    const float* __restrict__ b2,
    const unsigned short* __restrict__ w1cat_next, // [512][256] or null
    const float* __restrict__ b1e_next,            // [512] or null
    unsigned short* __restrict__ hT,               // [NN][HTS] out (if w1cat_next)
    const unsigned short* __restrict__ w_out_t,    // [64][256] (used if last)
    const float* __restrict__ b_out,               // [64]
    float* __restrict__ outF)                      // [NN][64] fp32 (used if last)
{
  __shared__ __align__(16) unsigned short As[SR*32];      // 2 KB
  __shared__ __align__(16) unsigned short Bs[256*32];     // 16 KB
  __shared__ __align__(16) unsigned short xL[8*SR*32];    // 16 KB (x1, then hcur strip)
  const int t = threadIdx.x;
  const int lane = t & 63, wave = t >> 6;
  const int ln15 = lane & 15, q = lane >> 4;
  const int bm = blockIdx.x;
  const int sc = (t & 3) * 8;
  const int srA = (t & 127) >> 2;      // 0..31 (A staging, threads 0..127)
  const int srB = t >> 2;              // 0..63 (B staging rows)

  const int rowA = bm*SR + srA;
  const unsigned short* aSrc = hcur + (size_t)rowA * HD + sc;
  float* gSrc = aggF + (size_t)rowA * HD + sc;

  float bv1[4], bv2[4];
  #pragma unroll
  for (int j = 0; j < 4; ++j) {
    bv1[j] = b1[wave*64 + j*16 + ln15];
    bv2[j] = b2[wave*64 + j*16 + ln15];
  }

  f32x4 acc[2][4];
  #pragma unroll
  for (int i = 0; i < 2; ++i)
    #pragma unroll
    for (int j = 0; j < 4; ++j) acc[i][j] = (f32x4){0.f,0.f,0.f,0.f};

  // ---------- phase A: K = 512 over [hcur | bf16(aggF)] ----------
  for (int kt = 0; kt < 16; ++kt) {
    if (t < 128) {
      if (kt < 8) {
        async16(aSrc + kt*32, &As[t*8]);
      } else {
        float* p = gSrc + (kt-8)*32;
        float4 a0 = *(const float4*)p;
        float4 a1 = *(const float4*)(p + 4);
        union { unsigned int u[4]; short8 s8; } cv;
        cv.u[0] = pk2bf(a0.x, a0.y); cv.u[1] = pk2bf(a0.z, a0.w);
        cv.u[2] = pk2bf(a1.x, a1.y); cv.u[3] = pk2bf(a1.z, a1.w);
        // zero the strip for next layer's edge_k
        *(float4*)p = float4{0.f,0.f,0.f,0.f};
        *(float4*)(p + 4) = float4{0.f,0.f,0.f,0.f};
        *(short8*)&As[t*8] = cv.s8;
      }
    }
    #pragma unroll
    for (int i = 0; i < 4; ++i)
      async16(w1t + (size_t)(i*64 + srB) * 512 + kt*32 + sc, &Bs[i*2048 + t*8]);
    __syncthreads();
    short8 fa[2], fb[4];
    #pragma unroll
    for (int i = 0; i < 2; ++i) fa[i] = *(const short8*)&As[(i*16 + ln15)*32 + q*8];
    #pragma unroll
    for (int j = 0; j < 4; ++j) fb[j] = *(const short8*)&Bs[(wave*64 + j*16 + ln15)*32 + q*8];
    #pragma unroll
    for (int i = 0; i < 2; ++i)
      #pragma unroll
      for (int j = 0; j < 4; ++j)
        acc[i][j] = __builtin_amdgcn_mfma_f32_16x16x32_bf16(fa[i], fb[j], acc[i][j], 0, 0, 0);
    __syncthreads();
  }

  // x1 = silu(acc + b1) -> xL (kt2-blocked: [kt2][row][k&31])
  #pragma unroll
  for (int i = 0; i < 2; ++i) {
    #pragma unroll
    for (int j = 0; j < 4; ++j) {
      const int k = wave*64 + j*16 + ln15;
      const int kt2 = k >> 5, k31 = k & 31;
      const f32x2 bb = (f32x2){bv1[j], bv1[j]};
      f32x2 s01 = (f32x2){acc[i][j][0], acc[i][j][1]} + bb;
      f32x2 s23 = (f32x2){acc[i][j][2], acc[i][j][3]} + bb;
      f32x2 r01 = silu2(s01);
      f32x2 r23 = silu2(s23);
      const int r0 = i*16 + q*4;
      xL[kt2*1024 + (r0  )*32 + k31] = f2bf(r01.x);
      xL[kt2*1024 + (r0+1)*32 + k31] = f2bf(r01.y);
      xL[kt2*1024 + (r0+2)*32 + k31] = f2bf(r23.x);
      xL[kt2*1024 + (r0+3)*32 + k31] = f2bf(r23.y);
    }
  }
  #pragma unroll
  for (int i = 0; i < 2; ++i)
    #pragma unroll
    for (int j = 0; j < 4; ++j) acc[i][j] = (f32x4){0.f,0.f,0.f,0.f};

  // ---------- phase B: K = 256, A = x1 (LDS), B = W2t ----------
  for (int kt2 = 0; kt2 < 8; ++kt2) {
    #pragma unroll
    for (int i = 0; i < 4; ++i)
      async16(w2t + (size_t)(i*64 + srB) * 256 + kt2*32 + sc, &Bs[i*2048 + t*8]);
    __syncthreads();
    short8 fa[2], fb[4];
    #pragma unroll
    for (int i = 0; i < 2; ++i) fa[i] = *(const short8*)&xL[kt2*1024 + (i*16 + ln15)*32 + q*8];
    #pragma unroll
    for (int j = 0; j < 4; ++j) fb[j] = *(const short8*)&Bs[(wave*64 + j*16 + ln15)*32 + q*8];
    #pragma unroll
    for (int i = 0; i < 2; ++i)
      #pragma unroll
      for (int j = 0; j < 4; ++j)
        acc[i][j] = __builtin_amdgcn_mfma_f32_16x16x32_bf16(fa[i], fb[j], acc[i][j], 0, 0, 0);
    __syncthreads();
  }

  // epilogue B: hcur = acc + b2 (no silu) -> global, AND strip -> xL for phase C/D
  #pragma unroll
  for (int i = 0; i < 2; ++i) {
    #pragma unroll
    for (int j = 0; j < 4; ++j) {
      const int n = wave*64 + j*16 + ln15;
      const int kt2 = n >> 5, k31 = n & 31;
      const int r0 = i*16 + q*4;
      const int m0 = bm*SR + r0;
      #pragma unroll
      for (int r = 0; r < 4; ++r) {
        unsigned short h = f2bf(acc[i][j][r] + bv2[j]);
        hcur[(size_t)(m0 + r) * HD + n] = h;
        xL[kt2*1024 + (r0 + r)*32 + k31] = h;
      }
    }
  }

  if (w1cat_next) {
    // ---------- phase C: hT strip = hcur_strip @ ew1cat_next^T + b1e_next ----------
    #pragma unroll
    for (int half = 0; half < 2; ++half) {
      #pragma unroll
      for (int i = 0; i < 2; ++i)
        #pragma unroll
        for (int j = 0; j < 4; ++j) acc[i][j] = (f32x4){0.f,0.f,0.f,0.f};
      for (int kt2 = 0; kt2 < 8; ++kt2) {
        #pragma unroll
        for (int i = 0; i < 4; ++i)
          async16(w1cat_next + (size_t)(half*256 + i*64 + srB) * 256 + kt2*32 + sc,
                  &Bs[i*2048 + t*8]);
        __syncthreads();
        short8 fa[2], fb[4];
        #pragma unroll
        for (int i = 0; i < 2; ++i) fa[i] = *(const short8*)&xL[kt2*1024 + (i*16 + ln15)*32 + q*8];
        #pragma unroll
        for (int j = 0; j < 4; ++j) fb[j] = *(const short8*)&Bs[(wave*64 + j*16 + ln15)*32 + q*8];
        #pragma unroll
        for (int i = 0; i < 2; ++i)
          #pragma unroll
          for (int j = 0; j < 4; ++j)
            acc[i][j] = __builtin_amdgcn_mfma_f32_16x16x32_bf16(fa[i], fb[j], acc[i][j], 0, 0, 0);
        __syncthreads();
      }
      #pragma unroll
      for (int i = 0; i < 2; ++i) {
        #pragma unroll
        for (int j = 0; j < 4; ++j) {
          const int n = half*256 + wave*64 + j*16 + ln15;
          const float bv = b1e_next[n];
          #pragma unroll
          for (int r = 0; r < 4; ++r) {
            const int m = bm*SR + i*16 + q*4 + r;
            hT[(size_t)m * HTS + n] = f2bf(acc[i][j][r] + bv);
          }
        }
      }
    }
  } else {
    // ---------- phase D: out = hcur_strip @ w_out^T + b_out (N=64, fp32) ----------
    const int nD = wave*16 + ln15;             // 0..63
    const float bvD = b_out[nD];
    f32x4 accD[2];
    accD[0] = (f32x4){0.f,0.f,0.f,0.f};
    accD[1] = (f32x4){0.f,0.f,0.f,0.f};
    for (int kt2 = 0; kt2 < 8; ++kt2) {
      // stage w_out_t rows 0..63, k-slice kt2*32 (one async16 per thread)
      async16(w_out_t + (size_t)srB * 256 + kt2*32 + sc, &Bs[t*8]);
      __syncthreads();
      short8 fa[2], fb;
      #pragma unroll
      for (int i = 0; i < 2; ++i) fa[i] = *(const short8*)&xL[kt2*1024 + (i*16 + ln15)*32 + q*8];
      fb = *(const short8*)&Bs[nD*32 + q*8];
      #pragma unroll
      for (int i = 0; i < 2; ++i)
        accD[i] = __builtin_amdgcn_mfma_f32_16x16x32_bf16(fa[i], fb, accD[i], 0, 0, 0);
      __syncthreads();
    }
    #pragma unroll
    for (int i = 0; i < 2; ++i) {
      #pragma unroll
      for (int r = 0; r < 4; ++r) {
        const int m = bm*SR + i*16 + q*4 + r;
        outF[(size_t)m * NF + nD] = accD[i][r] + bvD;
      }
    }
  }
}

// ---------------- fused edge MLP + aggregation (bf16 hT, stride-640 destagger) --------
__global__ __launch_bounds__(256, 4) void edge_k(
    const unsigned short* __restrict__ hT,   // [NN][HTS] bf16, cols 0..511 valid
    const int* __restrict__ rowcol,          // [NE][2] sorted (row,col)
    const float* __restrict__ radial_s,      // [NE] sorted radial
    const float* __restrict__ w1r,           // [256]
    const unsigned short* __restrict__ w2t,  // [256][256]
    const float* __restrict__ b2,
    float* __restrict__ agg)                  // [NN][256] fp32, pre-zeroed
{
  __shared__ __align__(16) unsigned short MBUF[16896];   // 33.8 KB
  __shared__ int   rowS[64];
  __shared__ float w1rS[256];
  unsigned short* M1  = MBUF;
  unsigned short* m2T = MBUF;

  const int t = threadIdx.x;
  const int lane = t & 63, wave = t >> 6;
  const int ln15 = lane & 15, q = lane >> 4;
  // chunked XCD swizzle: XCD k owns a contiguous 1/8 of sorted-edge space (hr L2 reuse)
  int blk = blockIdx.x;
  blk = (blk & 7) * ((int)gridDim.x >> 3) + (blk >> 3);
  const int e0 = blk * 64;
  const int sr = t >> 2;
  const int sc_swz = (((t & 3) ^ ((sr >> 1) & 3))) * 8;
  const int xq = ((q ^ ((ln15 >> 1) & 3))) * 8;

  // early small loads (before the 16 gathers: vmcnt retires in issue order)
  const int2 rc = *(const int2*)(rowcol + 2*(e0 + sr));   // gather base (1 load)
  int rowv = 0;
  if (t < 64) rowv = rowcol[2*(e0 + t)];
  const float w1v = w1r[t];
  const float rad = radial_s[e0 + sr];

  float bv2[4];
  #pragma unroll
  for (int j = 0; j < 4; ++j) bv2[j] = b2[wave*64 + j*16 + ln15];

  const unsigned short* hr = hT + (size_t)rc.x * HTS + sc_swz;
  const unsigned short* hc = hT + (size_t)rc.y * HTS + 256 + sc_swz;

  // batch all 16 gather b128s into registers, interleaved
  short8 va[8], vb[8];
  #pragma unroll
  for (int ch = 0; ch < 8; ++ch) {
    va[ch] = *(const short8*)(hr + ch*32);
    vb[ch] = *(const short8*)(hc + ch*32);
  }

  if (t < 64) rowS[t] = rowv;
  w1rS[t] = w1v;

  const unsigned short* w2row[4];
  #pragma unroll
  for (int j = 0; j < 4; ++j)
    w2row[j] = w2t + (size_t)(wave*64 + j*16 + ln15) * HD + q*8;

  __syncthreads();

  // prologue: m1 = silu(hr + hc + rad*w1r) -> M1 (kt-blocked, swizzled), b128 stores
  const f32x2 rad2 = (f32x2){rad, rad};
  #pragma unroll
  for (int ch = 0; ch < 8; ++ch) {
    const int c0 = ch*32 + sc_swz;
    const unsigned int* ua = (const unsigned int*)&va[ch];
    const unsigned int* ub = (const unsigned int*)&vb[ch];
    union { unsigned int u[4]; short8 s; } res;
    #pragma unroll
    for (int i = 0; i < 4; ++i) {
      union { unsigned int i; float f; } alo, ahi, blo, bhi;
      alo.i = ua[i] << 16; ahi.i = ua[i] & 0xFFFF0000u;
      blo.i = ub[i] << 16; bhi.i = ub[i] & 0xFFFF0000u;
      f32x2 av = (f32x2){alo.f, ahi.f};
      f32x2 bv = (f32x2){blo.f, bhi.f};
      f32x2 wv = *(const f32x2*)&w1rS[c0 + 2*i];
      f32x2 o = av + bv;
      o = o + rad2 * wv;            // pk fma
      f32x2 sv = silu2(o);
      res.u[i] = pk2bf(sv.x, sv.y);
    }
    *(short8*)&M1[ch*2048 + sr*32 + (t & 3)*8] = res.s;
  }
  __syncthreads();

  // phase 2: K = 256 (M1 @ W2^T); fb direct from global (L2-resident w2t)
  f32x4 acc2[4][4];
  #pragma unroll
  for (int i = 0; i < 4; ++i)
    #pragma unroll
    for (int j = 0; j < 4; ++j) acc2[i][j] = (f32x4){0.f,0.f,0.f,0.f};

  __builtin_amdgcn_s_setprio(1);
  #pragma unroll
  for (int kt = 0; kt < 8; ++kt) {
    short8 fa[4], fb[4];
    #pragma unroll
    for (int j = 0; j < 4; ++j) fb[j] = *(const short8*)(w2row[j] + kt*32);
    #pragma unroll
    for (int i = 0; i < 4; ++i) fa[i] = *(const short8*)&M1[kt*2048 + (i*16 + ln15)*32 + xq];
    #pragma unroll
    for (int i = 0; i < 4; ++i)
      #pragma unroll
      for (int j = 0; j < 4; ++j)
        acc2[i][j] = __builtin_amdgcn_mfma_f32_16x16x32_bf16(fa[i], fb[j], acc2[i][j], 0, 0, 0);
  }
  __builtin_amdgcn_s_setprio(0);
  __syncthreads();

  // epilogue 2a: silu -> m2T[col][stride 66] in LDS (pk math)
  #pragma unroll
  for (int i = 0; i < 4; ++i) {
    #pragma unroll
    for (int j = 0; j < 4; ++j) {
      const int n = wave*64 + j*16 + ln15;
      const f32x2 b2v = (f32x2){bv2[j], bv2[j]};
      f32x2 s01 = (f32x2){acc2[i][j][0], acc2[i][j][1]} + b2v;
      f32x2 s23 = (f32x2){acc2[i][j][2], acc2[i][j][3]} + b2v;
      f32x2 r01 = silu2(s01);
      f32x2 r23 = silu2(s23);
      const int m = i*16 + q*4;
      *(unsigned int*)&m2T[n*66 + m]     = pk2bf(r01.x, r01.y);
      *(unsigned int*)&m2T[n*66 + m + 2] = pk2bf(r23.x, r23.y);
    }
  }
  __syncthreads();

  // epilogue 2b: per-column segmented reduction (rowS readfirstlane -> scalar cmps)
  {
    const int c = t;
    int cur = __builtin_amdgcn_readfirstlane(rowS[0]);
    float s = 0.f;
    #pragma unroll
    for (int m = 0; m < 64; m += 4) {
      unsigned int u0 = *(const unsigned int*)&m2T[c*66 + m];
      unsigned int u1 = *(const unsigned int*)&m2T[c*66 + m + 2];
      int n0 = __builtin_amdgcn_readfirstlane(rowS[m]);
      int n1 = __builtin_amdgcn_readfirstlane(rowS[m+1]);
      int n2 = __builtin_amdgcn_readfirstlane(rowS[m+2]);
      int n3 = __builtin_amdgcn_readfirstlane(rowS[m+3]);
      float f0 = bf2f((unsigned short)u0), f1 = bf2f((unsigned short)(u0 >> 16));
      float f2v = bf2f((unsigned short)u1), f3 = bf2f((unsigned short)(u1 >> 16));
      if (n0 != cur) { atomicAdd(&agg[(size_t)cur * HD + c], s); s = 0.f; cur = n0; }
      s += f0;
      if (n1 != cur) { atomicAdd(&agg[(size_t)cur * HD + c], s); s = 0.f; cur = n1; }
      s += f1;
      if (n2 != cur) { atomicAdd(&agg[(size_t)cur * HD + c], s); s = 0.f; cur = n2; }
      s += f2v;
      if (n3 != cur) { atomicAdd(&agg[(size_t)cur * HD + c], s); s = 0.f; cur = n3; }
      s += f3;
    }
    atomicAdd(&agg[(size_t)cur * HD + c], s);
  }
}

// ---------------- launch ----------------
extern "C" void kernel_launch(void* const* d_in, const int* in_sizes, int n_in,
                              void* d_out, int out_size, void* d_ws, size_t ws_size,
                              hipStream_t stream)
{
  (void)in_sizes; (void)n_in; (void)out_size; (void)ws_size;
  const float* h_in  = (const float*)d_in[0];
  const int*   ei    = (const int*)d_in[1];
  const float* cd    = (const float*)d_in[2];
  const float* w_in  = (const float*)d_in[3];
  const float* b_in  = (const float*)d_in[4];
  const float* w_out = (const float*)d_in[5];
  const float* b_out = (const float*)d_in[6];
  const float* ew1   = (const float*)d_in[7];
  const float* eb1   = (const float*)d_in[8];
  const float* ew2   = (const float*)d_in[9];
  const float* eb2   = (const float*)d_in[10];
  const float* nw1   = (const float*)d_in[11];
  const float* nb1   = (const float*)d_in[12];
  const float* nw2   = (const float*)d_in[13];
  const float* nb2   = (const float*)d_in[14];
  float* out = (float*)d_out;

  char* base = (char*)d_ws;
  size_t off = 0;
  auto WS = [&](size_t bytes) -> char* {
    char* p = base + off;
    off = (off + bytes + 255) & ~(size_t)255;
    return p;
  };
  float*          radial  = (float*)WS((size_t)NE * 4);
  unsigned short* hb_in   = (unsigned short*)WS((size_t)NN * NF * 2);
  unsigned short* hcur    = (unsigned short*)WS((size_t)NN * HD * 2);
  float*          aggF    = (float*)WS((size_t)NN * HD * 4);
  unsigned short* hT      = (unsigned short*)WS((size_t)NN * HTS * 2);  // 25.6 MB bf16
  unsigned short* w_in_t  = (unsigned short*)WS((size_t)NF * HD * 2);
  unsigned short* w_out_t = (unsigned short*)WS((size_t)NF * HD * 2);
  unsigned short* ew1cat  = (unsigned short*)WS((size_t)NL * 512 * 256 * 2);
  float*          w1r     = (float*)WS((size_t)NL * HD * 4);
  float*          b1e     = (float*)WS((size_t)NL * 512 * 4);
  unsigned short* ew2t    = (unsigned short*)WS((size_t)NL * HD * HD * 2);
  unsigned short* nw1t    = (unsigned short*)WS((size_t)NL * HD * 512 * 2);
  unsigned short* nw2t    = (unsigned short*)WS((size_t)NL * HD * HD * 2);
  int*            hist    = (int*)WS((size_t)NN * 4);
  int*            bsum    = (int*)WS((size_t)128 * 4);
  int*            boff    = (int*)WS((size_t)128 * 4);
  int*            cursor  = (int*)WS((size_t)NN * 4);
  int*            rowcol  = (int*)WS((size_t)NE * 2 * 4);
  float*          radial_s= (float*)WS((size_t)NE * 4);

  hipMemsetAsync(hist, 0, (size_t)NN * 4, stream);
  hipMemsetAsync(aggF, 0, (size_t)NN * HD * 4, stream);
  prep_small<<<dim3(513, 19), 256, 0, stream>>>(w_in, w_out, ew1, ew2, nw1, nw2, eb1,
      w_in_t, w_out_t, ew1cat, w1r, b1e, ew2t, nw1t, nw2t);
  prep_big<<<dim3(5000, 2), 256, 0, stream>>>(h_in, cd, hb_in, radial);
  hist_k<<<NE / 256, 256, 0, stream>>>(ei, hist);
  scan1_k<<<NB, 256, 0, stream>>>(hist, bsum);
  scan2_k<<<1, 256, 0, stream>>>(bsum, boff);
  scan3_k<<<NB, 256, 0, stream>>>(hist, boff, cursor);
  scatter_k<<<NE / 256, 256, 0, stream>>>(ei, ei + NE, radial, cursor, rowcol, radial_s);

  // embedding + layer-0 hT table, fused per 32-row strip
  node0_k<<<NN / SR, 256, 0, stream>>>(hb_in, w_in_t, b_in, ew1cat, b1e, hcur, hT);

  for (int l = 0; l < NL; ++l) {
    edge_k<<<NE / 64, 256, 0, stream>>>(hT, rowcol, radial_s,
        w1r + l * HD, ew2t + (size_t)l * HD * HD, eb2 + l * HD, aggF);
    const int last = (l == NL - 1);
    node_k<<<NN / SR, 256, 0, stream>>>(hcur, aggF,
        nw1t + (size_t)l * HD * 512, nb1 + l * HD,
        nw2t + (size_t)l * HD * HD, nb2 + l * HD,
        last ? nullptr : (ew1cat + (size_t)(l+1) * 512 * 256),
        last ? nullptr : (b1e + (size_t)(l+1) * 512),
        hT, w_out_t, b_out, out);
  }
}

// Round 11
// 1101.590 us; speedup vs baseline: 1.1312x; 1.0026x over previous
//
#include <hip/hip_runtime.h>
#include <hip/hip_bf16.h>
#include <cstdint>
#include <cstddef>

#define NN 20000
#define NE 640000
#define NF 64
#define HD 256
#define NL 4
#define HTS 640   // hT row stride in shorts: 1280 B = 5x256 B (destaggers HBM channels)
#define SR 32     // node strip rows (R7-proven)
#define NB 79     // scan blocks: ceil(NN/256)
#define EB 128    // edges per edge_k block (128-row A-tile: m97-class geometry)

typedef __attribute__((ext_vector_type(8))) short short8;
typedef __attribute__((ext_vector_type(4))) float f32x4;
typedef __attribute__((ext_vector_type(2))) float f32x2;

__device__ __forceinline__ float bf2f(unsigned short u){
  union { unsigned int i; float f; } x; x.i = ((unsigned int)u) << 16; return x.f;
}
__device__ __forceinline__ unsigned short f2bf(float f){
  union { float f; unsigned int i; } x; x.f = f;
  unsigned int r = x.i + 0x7FFFu + ((x.i >> 16) & 1u);   // RNE
  return (unsigned short)(r >> 16);
}
// packed 2xf32 -> 2xbf16 (v_cvt_pk_bf16_f32 on gfx950, RNE)
__device__ __forceinline__ unsigned int pk2bf(float a, float b){
  union { __hip_bfloat162 h; unsigned int u; } cv;
  cv.h = __float22bfloat162_rn(float2{a, b});
  return cv.u;
}
// silu via guaranteed-native v_exp_f32 + v_rcp_f32
__device__ __forceinline__ float silu_f(float v){
  float e = __builtin_amdgcn_exp2f(v * -1.442695041f);
  return v * __builtin_amdgcn_rcpf(1.0f + e);
}
// packed silu on 2 lanes: pk mul/add around the 2 scalar trans ops
__device__ __forceinline__ f32x2 silu2(f32x2 v){
  f32x2 t = v * (f32x2){-1.442695041f, -1.442695041f};   // v_pk_mul_f32
  f32x2 e = (f32x2){__builtin_amdgcn_exp2f(t.x), __builtin_amdgcn_exp2f(t.y)};
  f32x2 d = e + (f32x2){1.0f, 1.0f};                      // v_pk_add_f32
  f32x2 r = (f32x2){__builtin_amdgcn_rcpf(d.x), __builtin_amdgcn_rcpf(d.y)};
  return v * r;                                           // v_pk_mul_f32
}
__device__ __forceinline__ void async16(const void* g, void* l){
  __builtin_amdgcn_global_load_lds(
      (const __attribute__((address_space(1))) unsigned int*)g,
      (__attribute__((address_space(3))) unsigned int*)l, 16, 0, 0);
}

// ---------------- prep_small: weight transposes -> bf16, b1e (513-block slices) -------
__global__ __launch_bounds__(256) void prep_small(
    const float* __restrict__ w_in, const float* __restrict__ w_out,
    const float* __restrict__ ew1, const float* __restrict__ ew2,
    const float* __restrict__ nw1, const float* __restrict__ nw2,
    const float* __restrict__ eb1,
    unsigned short* __restrict__ w_in_t, unsigned short* __restrict__ w_out_t,
    unsigned short* __restrict__ ew1cat, float* __restrict__ w1r,
    float* __restrict__ b1e,
    unsigned short* __restrict__ ew2t, unsigned short* __restrict__ nw1t,
    unsigned short* __restrict__ nw2t)
{
  const int s = blockIdx.y;
  const int tid = blockIdx.x * 256 + threadIdx.x;
  if (s == 18) {
    if (tid < NL * 512) {
      int l = tid >> 9, c = tid & 511;
      b1e[tid] = (c < 256) ? eb1[l * HD + c] : 0.0f;
    }
    return;
  }
  if (s >= 2 && s < 6) {
    int l = s - 2;
    if (tid >= 513 * HD) return;
    int k = tid / HD, n = tid - k * HD;
    float v = ew1[(size_t)l * 513 * HD + tid];
    if (k == 512) { w1r[l * HD + n] = v; return; }
    unsigned short* dst = ew1cat + (size_t)l * 512 * 256;
    if (k < 256) dst[(size_t)n * 256 + k] = f2bf(v);
    else         dst[(size_t)(256 + n) * 256 + (k - 256)] = f2bf(v);
    return;
  }
  const float* src; unsigned short* dst; int K, N;
  if (s == 0)      { src = w_in;  dst = w_in_t;  K = NF;   N = HD; }
  else if (s == 1) { src = w_out; dst = w_out_t; K = HD;   N = NF; }
  else if (s < 10) { int l = s-6;  src = ew2 + (size_t)l*HD*HD;   dst = ew2t + (size_t)l*HD*HD;  K = HD;   N = HD; }
  else if (s < 14) { int l = s-10; src = nw1 + (size_t)l*2*HD*HD; dst = nw1t + (size_t)l*HD*512; K = 2*HD; N = HD; }
  else             { int l = s-14; src = nw2 + (size_t)l*HD*HD;   dst = nw2t + (size_t)l*HD*HD;  K = HD;   N = HD; }
  if (tid >= K * N) return;
  int k = tid / N, n = tid - k * N;
  dst[(size_t)n * K + k] = f2bf(src[tid]);
}

// ---------------- prep_big: h->bf16, radial ----------------
__global__ __launch_bounds__(256) void prep_big(
    const float* __restrict__ h_in, const float* __restrict__ cd,
    unsigned short* __restrict__ hb_in, float* __restrict__ radial)
{
  const int s = blockIdx.y;
  const int tid = blockIdx.x * 256 + threadIdx.x;
  if (s == 0) {
    if (tid < NN * NF) hb_in[tid] = f2bf(h_in[tid]);
  } else {
    if (tid < NE) {
      float x = cd[tid*3+0], y = cd[tid*3+1], z = cd[tid*3+2];
      radial[tid] = x*x + y*y + z*z;
    }
  }
}

// ---------------- counting sort of edges by row (3-phase parallel scan) -------------
__global__ __launch_bounds__(256) void hist_k(const int* __restrict__ erow, int* __restrict__ hist){
  int e = blockIdx.x * 256 + threadIdx.x;
  if (e < NE){
    unsigned r = (unsigned)erow[e]; if (r >= NN) r = 0;
    atomicAdd(&hist[r], 1);
  }
}

__global__ __launch_bounds__(256) void scan1_k(const int* __restrict__ hist, int* __restrict__ bsum){
  __shared__ int red[256];
  const int t = threadIdx.x;
  const int bin = blockIdx.x * 256 + t;
  red[t] = (bin < NN) ? hist[bin] : 0;
  __syncthreads();
  for (int off = 128; off > 0; off >>= 1){
    if (t < off) red[t] += red[t + off];
    __syncthreads();
  }
  if (t == 0) bsum[blockIdx.x] = red[0];
}

__global__ __launch_bounds__(256) void scan2_k(const int* __restrict__ bsum, int* __restrict__ boff){
  __shared__ int part[256];
  const int t = threadIdx.x;
  int v = (t < NB) ? bsum[t] : 0;
  part[t] = v;
  __syncthreads();
  for (int off = 1; off < 256; off <<= 1){
    int p = (t >= off) ? part[t - off] : 0;
    __syncthreads();
    part[t] += p;
    __syncthreads();
  }
  if (t < NB) boff[t] = part[t] - v;   // exclusive
}

__global__ __launch_bounds__(256) void scan3_k(const int* __restrict__ hist,
                                               const int* __restrict__ boff,
                                               int* __restrict__ cursor){
  __shared__ int part[256];
  const int t = threadIdx.x;
  const int bin = blockIdx.x * 256 + t;
  int v = (bin < NN) ? hist[bin] : 0;
  part[t] = v;
  __syncthreads();
  for (int off = 1; off < 256; off <<= 1){
    int p = (t >= off) ? part[t - off] : 0;
    __syncthreads();
    part[t] += p;
    __syncthreads();
  }
  if (bin < NN) cursor[bin] = boff[blockIdx.x] + part[t] - v;   // exclusive
}

// scatter materializes (row,col) pairs and re-sorted radial at the sorted slot
__global__ __launch_bounds__(256) void scatter_k(const int* __restrict__ erow,
                                                 const int* __restrict__ ecol,
                                                 const float* __restrict__ radial,
                                                 int* __restrict__ cursor,
                                                 int* __restrict__ rowcol,
                                                 float* __restrict__ radial_s){
  int e = blockIdx.x * 256 + threadIdx.x;
  if (e < NE){
    unsigned r = (unsigned)erow[e]; if (r >= NN) r = 0;
    unsigned c = (unsigned)ecol[e]; if (c >= NN) c = 0;
    int pos = atomicAdd(&cursor[r], 1);
    rowcol[2*pos]   = (int)r;
    rowcol[2*pos+1] = (int)c;
    radial_s[pos] = radial[e];
  }
}

// ---------------- node0_k: hcur = hb@w_in^T+b_in; hT = hcur@ew1cat0^T+b1e0 ----------
// R7/R10-proven: 32-row strips; Bs staged via async16 (pipelined); strip in LDS.
__global__ __launch_bounds__(256, 4) void node0_k(
    const unsigned short* __restrict__ hb,      // [NN][64] bf16
    const unsigned short* __restrict__ w_in_t,  // [256][64]
    const float* __restrict__ b_in,
    const unsigned short* __restrict__ w1cat0,  // [512][256]
    const float* __restrict__ b1e0,             // [512]
    unsigned short* __restrict__ hcur,          // [NN][256] out
    unsigned short* __restrict__ hT)            // [NN][HTS] out
{
  __shared__ __align__(16) unsigned short As[SR*64];      // 4 KB
  __shared__ __align__(16) unsigned short Bs[256*32];     // 16 KB
  __shared__ __align__(16) unsigned short xL[8*SR*32];    // 16 KB (hcur strip)
  const int t = threadIdx.x;
  const int lane = t & 63, wave = t >> 6;
  const int ln15 = lane & 15, q = lane >> 4;
  const int bm = blockIdx.x;
  const int sc = (t & 3) * 8;
  const int srB = t >> 2;              // 0..63

  float bvin[4];
  #pragma unroll
  for (int j = 0; j < 4; ++j) bvin[j] = b_in[wave*64 + j*16 + ln15];

  f32x4 acc[2][4];
  #pragma unroll
  for (int i = 0; i < 2; ++i)
    #pragma unroll
    for (int j = 0; j < 4; ++j) acc[i][j] = (f32x4){0.f,0.f,0.f,0.f};

  // stage A strip once: [32][64] bf16
  async16(hb + (size_t)(bm*SR + (t >> 3)) * NF + (t & 7)*8, &As[t*8]);

  // ---------- phase A: K = 64, hcur_strip = hb_strip @ w_in_t^T + b_in ----------
  for (int kt = 0; kt < 2; ++kt) {
    #pragma unroll
    for (int i = 0; i < 4; ++i)
      async16(w_in_t + (size_t)(i*64 + srB) * NF + kt*32 + sc, &Bs[i*2048 + t*8]);
    __syncthreads();
    short8 fa[2], fb[4];
    #pragma unroll
    for (int i = 0; i < 2; ++i) fa[i] = *(const short8*)&As[(i*16 + ln15)*64 + kt*32 + q*8];
    #pragma unroll
    for (int j = 0; j < 4; ++j) fb[j] = *(const short8*)&Bs[(wave*64 + j*16 + ln15)*32 + q*8];
    #pragma unroll
    for (int i = 0; i < 2; ++i)
      #pragma unroll
      for (int j = 0; j < 4; ++j)
        acc[i][j] = __builtin_amdgcn_mfma_f32_16x16x32_bf16(fa[i], fb[j], acc[i][j], 0, 0, 0);
    __syncthreads();
  }

  // epilogue A: hcur = acc + b_in (no silu) -> global + xL
  #pragma unroll
  for (int i = 0; i < 2; ++i) {
    #pragma unroll
    for (int j = 0; j < 4; ++j) {
      const int n = wave*64 + j*16 + ln15;
      const int kt2 = n >> 5, k31 = n & 31;
      const int r0 = i*16 + q*4;
      const int m0 = bm*SR + r0;
      #pragma unroll
      for (int r = 0; r < 4; ++r) {
        unsigned short h = f2bf(acc[i][j][r] + bvin[j]);
        hcur[(size_t)(m0 + r) * HD + n] = h;
        xL[kt2*1024 + (r0 + r)*32 + k31] = h;
      }
    }
  }

  // ---------- phase C: hT strip = hcur_strip @ w1cat0^T + b1e0 ----------
  #pragma unroll
  for (int half = 0; half < 2; ++half) {
    #pragma unroll
    for (int i = 0; i < 2; ++i)
      #pragma unroll
      for (int j = 0; j < 4; ++j) acc[i][j] = (f32x4){0.f,0.f,0.f,0.f};
    for (int kt2 = 0; kt2 < 8; ++kt2) {
      #pragma unroll
      for (int i = 0; i < 4; ++i)
        async16(w1cat0 + (size_t)(half*256 + i*64 + srB) * 256 + kt2*32 + sc,
                &Bs[i*2048 + t*8]);
      __syncthreads();
      short8 fa[2], fb[4];
      #pragma unroll
      for (int i = 0; i < 2; ++i) fa[i] = *(const short8*)&xL[kt2*1024 + (i*16 + ln15)*32 + q*8];
      #pragma unroll
      for (int j = 0; j < 4; ++j) fb[j] = *(const short8*)&Bs[(wave*64 + j*16 + ln15)*32 + q*8];
      #pragma unroll
      for (int i = 0; i < 2; ++i)
        #pragma unroll
        for (int j = 0; j < 4; ++j)
          acc[i][j] = __builtin_amdgcn_mfma_f32_16x16x32_bf16(fa[i], fb[j], acc[i][j], 0, 0, 0);
      __syncthreads();
    }
    #pragma unroll
    for (int i = 0; i < 2; ++i) {
      #pragma unroll
      for (int j = 0; j < 4; ++j) {
        const int n = half*256 + wave*64 + j*16 + ln15;
        const float bv = b1e0[n];
        #pragma unroll
        for (int r = 0; r < 4; ++r) {
          const int m = bm*SR + i*16 + q*4 + r;
          hT[(size_t)m * HTS + n] = f2bf(acc[i][j][r] + bv);
        }
      }
    }
  }
}

// ---------------- fused node MLP + next-layer hT (or final projection) ----------------
// R7/R10-proven: 32-row strips (625 blocks), Bs staged via async16.
__global__ __launch_bounds__(256, 4) void node_k(
    unsigned short* __restrict__ hcur,      // [NN][256] bf16, read (k<256) + write
    float* __restrict__ aggF,               // [NN][256] fp32, read (k>=256) + zero
    const unsigned short* __restrict__ w1t, // [256][512]
    const float* __restrict__ b1,
    const unsigned short* __restrict__ w2t, // [256][256]
    const float* __restrict__ b2,
    const unsigned short* __restrict__ w1cat_next, // [512][256] or null
    const float* __restrict__ b1e_next,            // [512] or null
    unsigned short* __restrict__ hT,               // [NN][HTS] out (if w1cat_next)
    const unsigned short* __restrict__ w_out_t,    // [64][256] (used if last)
    const float* __restrict__ b_out,               // [64]
    float* __restrict__ outF)                      // [NN][64] fp32 (used if last)
{
  __shared__ __align__(16) unsigned short As[SR*32];      // 2 KB
  __shared__ __align__(16) unsigned short Bs[256*32];     // 16 KB
  __shared__ __align__(16) unsigned short xL[8*SR*32];    // 16 KB (x1, then hcur strip)
  const int t = threadIdx.x;
  const int lane = t & 63, wave = t >> 6;
  const int ln15 = lane & 15, q = lane >> 4;
  const int bm = blockIdx.x;
  const int sc = (t & 3) * 8;
  const int srA = (t & 127) >> 2;      // 0..31 (A staging, threads 0..127)
  const int srB = t >> 2;              // 0..63 (B staging rows)

  const int rowA = bm*SR + srA;
  const unsigned short* aSrc = hcur + (size_t)rowA * HD + sc;
  float* gSrc = aggF + (size_t)rowA * HD + sc;

  float bv1[4], bv2[4];
  #pragma unroll
  for (int j = 0; j < 4; ++j) {
    bv1[j] = b1[wave*64 + j*16 + ln15];
    bv2[j] = b2[wave*64 + j*16 + ln15];
  }

  f32x4 acc[2][4];
  #pragma unroll
  for (int i = 0; i < 2; ++i)
    #pragma unroll
    for (int j = 0; j < 4; ++j) acc[i][j] = (f32x4){0.f,0.f,0.f,0.f};

  // ---------- phase A: K = 512 over [hcur | bf16(aggF)] ----------
  for (int kt = 0; kt < 16; ++kt) {
    if (t < 128) {
      if (kt < 8) {
        async16(aSrc + kt*32, &As[t*8]);
      } else {
        float* p = gSrc + (kt-8)*32;
        float4 a0 = *(const float4*)p;
        float4 a1 = *(const float4*)(p + 4);
        union { unsigned int u[4]; short8 s8; } cv;
        cv.u[0] = pk2bf(a0.x, a0.y); cv.u[1] = pk2bf(a0.z, a0.w);
        cv.u[2] = pk2bf(a1.x, a1.y); cv.u[3] = pk2bf(a1.z, a1.w);
        // zero the strip for next layer's edge_k
        *(float4*)p = float4{0.f,0.f,0.f,0.f};
        *(float4*)(p + 4) = float4{0.f,0.f,0.f,0.f};
        *(short8*)&As[t*8] = cv.s8;
      }
    }
    #pragma unroll
    for (int i = 0; i < 4; ++i)
      async16(w1t + (size_t)(i*64 + srB) * 512 + kt*32 + sc, &Bs[i*2048 + t*8]);
    __syncthreads();
    short8 fa[2], fb[4];
    #pragma unroll
    for (int i = 0; i < 2; ++i) fa[i] = *(const short8*)&As[(i*16 + ln15)*32 + q*8];
    #pragma unroll
    for (int j = 0; j < 4; ++j) fb[j] = *(const short8*)&Bs[(wave*64 + j*16 + ln15)*32 + q*8];
    #pragma unroll
    for (int i = 0; i < 2; ++i)
      #pragma unroll
      for (int j = 0; j < 4; ++j)
        acc[i][j] = __builtin_amdgcn_mfma_f32_16x16x32_bf16(fa[i], fb[j], acc[i][j], 0, 0, 0);
    __syncthreads();
  }

  // x1 = silu(acc + b1) -> xL (kt2-blocked: [kt2][row][k&31])
  #pragma unroll
  for (int i = 0; i < 2; ++i) {
    #pragma unroll
    for (int j = 0; j < 4; ++j) {
      const int k = wave*64 + j*16 + ln15;
      const int kt2 = k >> 5, k31 = k & 31;
      const f32x2 bb = (f32x2){bv1[j], bv1[j]};
      f32x2 s01 = (f32x2){acc[i][j][0], acc[i][j][1]} + bb;
      f32x2 s23 = (f32x2){acc[i][j][2], acc[i][j][3]} + bb;
      f32x2 r01 = silu2(s01);
      f32x2 r23 = silu2(s23);
      const int r0 = i*16 + q*4;
      xL[kt2*1024 + (r0  )*32 + k31] = f2bf(r01.x);
      xL[kt2*1024 + (r0+1)*32 + k31] = f2bf(r01.y);
      xL[kt2*1024 + (r0+2)*32 + k31] = f2bf(r23.x);
      xL[kt2*1024 + (r0+3)*32 + k31] = f2bf(r23.y);
    }
  }
  #pragma unroll
  for (int i = 0; i < 2; ++i)
    #pragma unroll
    for (int j = 0; j < 4; ++j) acc[i][j] = (f32x4){0.f,0.f,0.f,0.f};

  // ---------- phase B: K = 256, A = x1 (LDS), B = W2t ----------
  for (int kt2 = 0; kt2 < 8; ++kt2) {
    #pragma unroll
    for (int i = 0; i < 4; ++i)
      async16(w2t + (size_t)(i*64 + srB) * 256 + kt2*32 + sc, &Bs[i*2048 + t*8]);
    __syncthreads();
    short8 fa[2], fb[4];
    #pragma unroll
    for (int i = 0; i < 2; ++i) fa[i] = *(const short8*)&xL[kt2*1024 + (i*16 + ln15)*32 + q*8];
    #pragma unroll
    for (int j = 0; j < 4; ++j) fb[j] = *(const short8*)&Bs[(wave*64 + j*16 + ln15)*32 + q*8];
    #pragma unroll
    for (int i = 0; i < 2; ++i)
      #pragma unroll
      for (int j = 0; j < 4; ++j)
        acc[i][j] = __builtin_amdgcn_mfma_f32_16x16x32_bf16(fa[i], fb[j], acc[i][j], 0, 0, 0);
    __syncthreads();
  }

  // epilogue B: hcur = acc + b2 (no silu) -> global, AND strip -> xL for phase C/D
  #pragma unroll
  for (int i = 0; i < 2; ++i) {
    #pragma unroll
    for (int j = 0; j < 4; ++j) {
      const int n = wave*64 + j*16 + ln15;
      const int kt2 = n >> 5, k31 = n & 31;
      const int r0 = i*16 + q*4;
      const int m0 = bm*SR + r0;
      #pragma unroll
      for (int r = 0; r < 4; ++r) {
        unsigned short h = f2bf(acc[i][j][r] + bv2[j]);
        hcur[(size_t)(m0 + r) * HD + n] = h;
        xL[kt2*1024 + (r0 + r)*32 + k31] = h;
      }
    }
  }

  if (w1cat_next) {
    // ---------- phase C: hT strip = hcur_strip @ ew1cat_next^T + b1e_next ----------
    #pragma unroll
    for (int half = 0; half < 2; ++half) {
      #pragma unroll
      for (int i = 0; i < 2; ++i)
        #pragma unroll
        for (int j = 0; j < 4; ++j) acc[i][j] = (f32x4){0.f,0.f,0.f,0.f};
      for (int kt2 = 0; kt2 < 8; ++kt2) {
        #pragma unroll
        for (int i = 0; i < 4; ++i)
          async16(w1cat_next + (size_t)(half*256 + i*64 + srB) * 256 + kt2*32 + sc,
                  &Bs[i*2048 + t*8]);
        __syncthreads();
        short8 fa[2], fb[4];
        #pragma unroll
        for (int i = 0; i < 2; ++i) fa[i] = *(const short8*)&xL[kt2*1024 + (i*16 + ln15)*32 + q*8];
        #pragma unroll
        for (int j = 0; j < 4; ++j) fb[j] = *(const short8*)&Bs[(wave*64 + j*16 + ln15)*32 + q*8];
        #pragma unroll
        for (int i = 0; i < 2; ++i)
          #pragma unroll
          for (int j = 0; j < 4; ++j)
            acc[i][j] = __builtin_amdgcn_mfma_f32_16x16x32_bf16(fa[i], fb[j], acc[i][j], 0, 0, 0);
        __syncthreads();
      }
      #pragma unroll
      for (int i = 0; i < 2; ++i) {
        #pragma unroll
        for (int j = 0; j < 4; ++j) {
          const int n = half*256 + wave*64 + j*16 + ln15;
          const float bv = b1e_next[n];
          #pragma unroll
          for (int r = 0; r < 4; ++r) {
            const int m = bm*SR + i*16 + q*4 + r;
            hT[(size_t)m * HTS + n] = f2bf(acc[i][j][r] + bv);
          }
        }
      }
    }
  } else {
    // ---------- phase D: out = hcur_strip @ w_out^T + b_out (N=64, fp32) ----------
    const int nD = wave*16 + ln15;             // 0..63
    const float bvD = b_out[nD];
    f32x4 accD[2];
    accD[0] = (f32x4){0.f,0.f,0.f,0.f};
    accD[1] = (f32x4){0.f,0.f,0.f,0.f};
    for (int kt2 = 0; kt2 < 8; ++kt2) {
      async16(w_out_t + (size_t)srB * 256 + kt2*32 + sc, &Bs[t*8]);
      __syncthreads();
      short8 fa[2], fb;
      #pragma unroll
      for (int i = 0; i < 2; ++i) fa[i] = *(const short8*)&xL[kt2*1024 + (i*16 + ln15)*32 + q*8];
      fb = *(const short8*)&Bs[nD*32 + q*8];
      #pragma unroll
      for (int i = 0; i < 2; ++i)
        accD[i] = __builtin_amdgcn_mfma_f32_16x16x32_bf16(fa[i], fb, accD[i], 0, 0, 0);
      __syncthreads();
    }
    #pragma unroll
    for (int i = 0; i < 2; ++i) {
      #pragma unroll
      for (int r = 0; r < 4; ++r) {
        const int m = bm*SR + i*16 + q*4 + r;
        outF[(size_t)m * NF + nD] = accD[i][r] + bvD;
      }
    }
  }
}

// ---------------- fused edge MLP + aggregation: 128-edge tile ----------------
// 2 blocks/CU (LDS 69 KB, 256-reg budget). Two 64-edge groups share one phase-2
// GEMM: 8 fa frags reuse each fb (W2 traffic per FLOP halves), 32 MFMA/kt,
// per-block fixed costs amortize 2x, both groups' gathers can sit in flight.
__global__ __launch_bounds__(256, 2) void edge_k(
    const unsigned short* __restrict__ hT,   // [NN][HTS] bf16, cols 0..511 valid
    const int* __restrict__ rowcol,          // [NE][2] sorted (row,col)
    const float* __restrict__ radial_s,      // [NE] sorted radial
    const float* __restrict__ w1r,           // [256]
    const unsigned short* __restrict__ w2t,  // [256][256]
    const float* __restrict__ b2,
    float* __restrict__ agg)                  // [NN][256] fp32, pre-zeroed
{
  __shared__ __align__(16) unsigned short MBUF[33280];   // 66.6 KB: M1[8][128][32] / m2T[256][130]
  __shared__ int   rowS[EB];
  __shared__ float w1rS[256];
  unsigned short* M1  = MBUF;
  unsigned short* m2T = MBUF;

  const int t = threadIdx.x;
  const int lane = t & 63, wave = t >> 6;
  const int ln15 = lane & 15, q = lane >> 4;
  // chunked XCD swizzle: XCD k owns a contiguous 1/8 of sorted-edge space
  int blk = blockIdx.x;
  blk = (blk & 7) * ((int)gridDim.x >> 3) + (blk >> 3);
  const int e0 = blk * EB;
  const int sr = t >> 2;
  const int sc_swz = (((t & 3) ^ ((sr >> 1) & 3))) * 8;
  const int xq = ((q ^ ((ln15 >> 1) & 3))) * 8;

  // early small loads for BOTH groups (issued before gathers; vmcnt in-order)
  int2 rcg[2]; float radg[2];
  #pragma unroll
  for (int g = 0; g < 2; ++g) {
    rcg[g] = *(const int2*)(rowcol + 2*(e0 + g*64 + sr));
    radg[g] = radial_s[e0 + g*64 + sr];
  }
  int rowv = 0;
  if (t < EB) rowv = rowcol[2*(e0 + t)];
  const float w1v = w1r[t];

  float bv2[4];
  #pragma unroll
  for (int j = 0; j < 4; ++j) bv2[j] = b2[wave*64 + j*16 + ln15];

  // batch all 32 gather b128s (both groups) into registers
  short8 va[2][8], vb[2][8];
  #pragma unroll
  for (int g = 0; g < 2; ++g) {
    const unsigned short* hr = hT + (size_t)rcg[g].x * HTS + sc_swz;
    const unsigned short* hc = hT + (size_t)rcg[g].y * HTS + 256 + sc_swz;
    #pragma unroll
    for (int ch = 0; ch < 8; ++ch) {
      va[g][ch] = *(const short8*)(hr + ch*32);
      vb[g][ch] = *(const short8*)(hc + ch*32);
    }
  }

  if (t < EB) rowS[t] = rowv;
  w1rS[t] = w1v;

  const unsigned short* w2row[4];
  #pragma unroll
  for (int j = 0; j < 4; ++j)
    w2row[j] = w2t + (size_t)(wave*64 + j*16 + ln15) * HD + q*8;

  __syncthreads();

  // prologue: m1 = silu(hr + hc + rad*w1r) -> M1 (kt-blocked [8][128][32], swizzled)
  #pragma unroll
  for (int g = 0; g < 2; ++g) {
    const f32x2 rad2 = (f32x2){radg[g], radg[g]};
    #pragma unroll
    for (int ch = 0; ch < 8; ++ch) {
      const int c0 = ch*32 + sc_swz;
      const unsigned int* ua = (const unsigned int*)&va[g][ch];
      const unsigned int* ub = (const unsigned int*)&vb[g][ch];
      union { unsigned int u[4]; short8 s; } res;
      #pragma unroll
      for (int i = 0; i < 4; ++i) {
        union { unsigned int i; float f; } alo, ahi, blo, bhi;
        alo.i = ua[i] << 16; ahi.i = ua[i] & 0xFFFF0000u;
        blo.i = ub[i] << 16; bhi.i = ub[i] & 0xFFFF0000u;
        f32x2 av = (f32x2){alo.f, ahi.f};
        f32x2 bv = (f32x2){blo.f, bhi.f};
        f32x2 wv = *(const f32x2*)&w1rS[c0 + 2*i];
        f32x2 o = av + bv;
        o = o + rad2 * wv;            // pk fma
        f32x2 sv = silu2(o);
        res.u[i] = pk2bf(sv.x, sv.y);
      }
      *(short8*)&M1[ch*4096 + (g*64 + sr)*32 + (t & 3)*8] = res.s;
    }
  }
  __syncthreads();

  // phase 2: K = 256, M = 128 (M1 @ W2^T); fb direct from global (L2-resident w2t)
  f32x4 acc2[8][4];
  #pragma unroll
  for (int i = 0; i < 8; ++i)
    #pragma unroll
    for (int j = 0; j < 4; ++j) acc2[i][j] = (f32x4){0.f,0.f,0.f,0.f};

  __builtin_amdgcn_s_setprio(1);
  #pragma unroll
  for (int kt = 0; kt < 8; ++kt) {
    short8 fa[8], fb[4];
    #pragma unroll
    for (int j = 0; j < 4; ++j) fb[j] = *(const short8*)(w2row[j] + kt*32);
    #pragma unroll
    for (int i = 0; i < 8; ++i) fa[i] = *(const short8*)&M1[kt*4096 + (i*16 + ln15)*32 + xq];
    #pragma unroll
    for (int i = 0; i < 8; ++i)
      #pragma unroll
      for (int j = 0; j < 4; ++j)
        acc2[i][j] = __builtin_amdgcn_mfma_f32_16x16x32_bf16(fa[i], fb[j], acc2[i][j], 0, 0, 0);
  }
  __builtin_amdgcn_s_setprio(0);
  __syncthreads();

  // epilogue 2a: silu -> m2T[col][edge], stride 130 shorts (bank step 1)
  #pragma unroll
  for (int i = 0; i < 8; ++i) {
    #pragma unroll
    for (int j = 0; j < 4; ++j) {
      const int n = wave*64 + j*16 + ln15;
      const f32x2 b2v = (f32x2){bv2[j], bv2[j]};
      f32x2 s01 = (f32x2){acc2[i][j][0], acc2[i][j][1]} + b2v;
      f32x2 s23 = (f32x2){acc2[i][j][2], acc2[i][j][3]} + b2v;
      f32x2 r01 = silu2(s01);
      f32x2 r23 = silu2(s23);
      const int m = i*16 + q*4;
      *(unsigned int*)&m2T[n*130 + m]     = pk2bf(r01.x, r01.y);
      *(unsigned int*)&m2T[n*130 + m + 2] = pk2bf(r23.x, r23.y);
    }
  }
  __syncthreads();

  // epilogue 2b: per-column segmented reduction over 128 sorted edges
  {
    const int c = t;
    int cur = __builtin_amdgcn_readfirstlane(rowS[0]);
    float s = 0.f;
    #pragma unroll
    for (int m = 0; m < EB; m += 4) {
      unsigned int u0 = *(const unsigned int*)&m2T[c*130 + m];
      unsigned int u1 = *(const unsigned int*)&m2T[c*130 + m + 2];
      int n0 = __builtin_amdgcn_readfirstlane(rowS[m]);
      int n1 = __builtin_amdgcn_readfirstlane(rowS[m+1]);
      int n2 = __builtin_amdgcn_readfirstlane(rowS[m+2]);
      int n3 = __builtin_amdgcn_readfirstlane(rowS[m+3]);
      float f0 = bf2f((unsigned short)u0), f1 = bf2f((unsigned short)(u0 >> 16));
      float f2v = bf2f((unsigned short)u1), f3 = bf2f((unsigned short)(u1 >> 16));
      if (n0 != cur) { atomicAdd(&agg[(size_t)cur * HD + c], s); s = 0.f; cur = n0; }
      s += f0;
      if (n1 != cur) { atomicAdd(&agg[(size_t)cur * HD + c], s); s = 0.f; cur = n1; }
      s += f1;
      if (n2 != cur) { atomicAdd(&agg[(size_t)cur * HD + c], s); s = 0.f; cur = n2; }
      s += f2v;
      if (n3 != cur) { atomicAdd(&agg[(size_t)cur * HD + c], s); s = 0.f; cur = n3; }
      s += f3;
    }
    atomicAdd(&agg[(size_t)cur * HD + c], s);
  }
}

// ---------------- launch ----------------
extern "C" void kernel_launch(void* const* d_in, const int* in_sizes, int n_in,
                              void* d_out, int out_size, void* d_ws, size_t ws_size,
                              hipStream_t stream)
{
  (void)in_sizes; (void)n_in; (void)out_size; (void)ws_size;
  const float* h_in  = (const float*)d_in[0];
  const int*   ei    = (const int*)d_in[1];
  const float* cd    = (const float*)d_in[2];
  const float* w_in  = (const float*)d_in[3];
  const float* b_in  = (const float*)d_in[4];
  const float* w_out = (const float*)d_in[5];
  const float* b_out = (const float*)d_in[6];
  const float* ew1   = (const float*)d_in[7];
  const float* eb1   = (const float*)d_in[8];
  const float* ew2   = (const float*)d_in[9];
  const float* eb2   = (const float*)d_in[10];
  const float* nw1   = (const float*)d_in[11];
  const float* nb1   = (const float*)d_in[12];
  const float* nw2   = (const float*)d_in[13];
  const float* nb2   = (const float*)d_in[14];
  float* out = (float*)d_out;

  char* base = (char*)d_ws;
  size_t off = 0;
  auto WS = [&](size_t bytes) -> char* {
    char* p = base + off;
    off = (off + bytes + 255) & ~(size_t)255;
    return p;
  };
  float*          radial  = (float*)WS((size_t)NE * 4);
  unsigned short* hb_in   = (unsigned short*)WS((size_t)NN * NF * 2);
  unsigned short* hcur    = (unsigned short*)WS((size_t)NN * HD * 2);
  float*          aggF    = (float*)WS((size_t)NN * HD * 4);
  unsigned short* hT      = (unsigned short*)WS((size_t)NN * HTS * 2);  // 25.6 MB bf16
  unsigned short* w_in_t  = (unsigned short*)WS((size_t)NF * HD * 2);
  unsigned short* w_out_t = (unsigned short*)WS((size_t)NF * HD * 2);
  unsigned short* ew1cat  = (unsigned short*)WS((size_t)NL * 512 * 256 * 2);
  float*          w1r     = (float*)WS((size_t)NL * HD * 4);
  float*          b1e     = (float*)WS((size_t)NL * 512 * 4);
  unsigned short* ew2t    = (unsigned short*)WS((size_t)NL * HD * HD * 2);
  unsigned short* nw1t    = (unsigned short*)WS((size_t)NL * HD * 512 * 2);
  unsigned short* nw2t    = (unsigned short*)WS((size_t)NL * HD * HD * 2);
  int*            hist    = (int*)WS((size_t)NN * 4);
  int*            bsum    = (int*)WS((size_t)128 * 4);
  int*            boff    = (int*)WS((size_t)128 * 4);
  int*            cursor  = (int*)WS((size_t)NN * 4);
  int*            rowcol  = (int*)WS((size_t)NE * 2 * 4);
  float*          radial_s= (float*)WS((size_t)NE * 4);

  hipMemsetAsync(hist, 0, (size_t)NN * 4, stream);
  hipMemsetAsync(aggF, 0, (size_t)NN * HD * 4, stream);
  prep_small<<<dim3(513, 19), 256, 0, stream>>>(w_in, w_out, ew1, ew2, nw1, nw2, eb1,
      w_in_t, w_out_t, ew1cat, w1r, b1e, ew2t, nw1t, nw2t);
  prep_big<<<dim3(5000, 2), 256, 0, stream>>>(h_in, cd, hb_in, radial);
  hist_k<<<NE / 256, 256, 0, stream>>>(ei, hist);
  scan1_k<<<NB, 256, 0, stream>>>(hist, bsum);
  scan2_k<<<1, 256, 0, stream>>>(bsum, boff);
  scan3_k<<<NB, 256, 0, stream>>>(hist, boff, cursor);
  scatter_k<<<NE / 256, 256, 0, stream>>>(ei, ei + NE, radial, cursor, rowcol, radial_s);

  // embedding + layer-0 hT table, fused per 32-row strip
  node0_k<<<NN / SR, 256, 0, stream>>>(hb_in, w_in_t, b_in, ew1cat, b1e, hcur, hT);

  for (int l = 0; l < NL; ++l) {
    edge_k<<<NE / EB, 256, 0, stream>>>(hT, rowcol, radial_s,
        w1r + l * HD, ew2t + (size_t)l * HD * HD, eb2 + l * HD, aggF);
    const int last = (l == NL - 1);
    node_k<<<NN / SR, 256, 0, stream>>>(hcur, aggF,
        nw1t + (size_t)l * HD * 512, nb1 + l * HD,
        nw2t + (size_t)l * HD * HD, nb2 + l * HD,
        last ? nullptr : (ew1cat + (size_t)(l+1) * 512 * 256),
        last ? nullptr : (b1e + (size_t)(l+1) * 512),
        hT, w_out_t, b_out, out);
  }
}